// Round 9
// baseline (365.087 us; speedup 1.0000x reference)
//
#include <hip/hip_runtime.h>
#include <math.h>

#define NN 50000
#define NE 800000
#define NEG 0.2f
#define NB 196  // ceil(NN/256)

// ---------- fused dual GEMM: out[N,256] = feat[N,128] @ W + b  (gridDim.y picks W1s/W1d)
// Wave-uniform A-rows (scalar loads, no LDS for feat); W in k-transposed LDS [g][col][4k].
__global__ __launch_bounds__(256) void gemm_proj(
    const float* __restrict__ feat,
    const float* __restrict__ Wa, const float* __restrict__ ba, float* __restrict__ outa,
    const float* __restrict__ Wb, const float* __restrict__ bb, float* __restrict__ outb,
    int n_rows)
{
    const float* W  = blockIdx.y ? Wb : Wa;
    const float* bv = blockIdx.y ? bb : ba;
    float* out      = blockIdx.y ? outb : outa;

    __shared__ float wTt[4][256][4];   // [g][col][j], k = k0 + 4g + j ; 16 KB

    const int tid = threadIdx.x;
    const int w   = __builtin_amdgcn_readfirstlane(tid >> 6);  // wave id 0..3 (uniform)
    const int tn  = tid & 63;
    const int row0 = blockIdx.x * 64;

    float acc[16][4];
#pragma unroll
    for (int ri = 0; ri < 16; ++ri)
#pragma unroll
        for (int ci = 0; ci < 4; ++ci) acc[ri][ci] = 0.0f;

    for (int c8 = 0; c8 < 8; ++c8) {
        const int k0 = c8 * 16;
        // load W chunk into regs (coalesced b32, L2-hot), issued before the barrier
        float wr[16];
#pragma unroll
        for (int p = 0; p < 4; ++p) {
            const int idx = p * 256 + tid;
            const int g = idx >> 8, col = idx & 255;
#pragma unroll
            for (int j = 0; j < 4; ++j)
                wr[p * 4 + j] = W[(size_t)(k0 + g * 4 + j) * 256 + col];
        }
        __syncthreads();   // previous chunk fully consumed
#pragma unroll
        for (int p = 0; p < 4; ++p) {
            const int idx = p * 256 + tid;
            const int g = idx >> 8, col = idx & 255;
            *reinterpret_cast<float4*>(&wTt[g][col][0]) =
                make_float4(wr[p * 4 + 0], wr[p * 4 + 1], wr[p * 4 + 2], wr[p * 4 + 3]);
        }
        __syncthreads();
#pragma unroll
        for (int g = 0; g < 4; ++g) {
            float4 w4[4];
#pragma unroll
            for (int ci = 0; ci < 4; ++ci)
                w4[ci] = *reinterpret_cast<const float4*>(&wTt[g][tn + ci * 64][0]);
#pragma unroll
            for (int ri = 0; ri < 16; ++ri) {
                const int row = row0 + w + ri * 4;
                const int rowc = (row < n_rows) ? row : n_rows - 1;   // uniform clamp
                const float4 af = *reinterpret_cast<const float4*>(
                    &feat[(size_t)rowc * 128 + k0 + g * 4]);          // scalar (SMEM) load
#pragma unroll
                for (int ci = 0; ci < 4; ++ci) {
                    acc[ri][ci] = fmaf(af.x, w4[ci].x, acc[ri][ci]);
                    acc[ri][ci] = fmaf(af.y, w4[ci].y, acc[ri][ci]);
                    acc[ri][ci] = fmaf(af.z, w4[ci].z, acc[ri][ci]);
                    acc[ri][ci] = fmaf(af.w, w4[ci].w, acc[ri][ci]);
                }
            }
        }
    }

    float bvv[4];
#pragma unroll
    for (int ci = 0; ci < 4; ++ci) bvv[ci] = bv[tn + ci * 64];
#pragma unroll
    for (int ri = 0; ri < 16; ++ri) {
        const int row = row0 + w + ri * 4;
        if (row < n_rows) {
#pragma unroll
            for (int ci = 0; ci < 4; ++ci)
                out[(size_t)row * 256 + tn + ci * 64] = acc[ri][ci] + bvv[ci];
        }
    }
}

// ---------------- CSR build ----------------
__global__ void count_deg(const int* __restrict__ dst, int* __restrict__ deg)
{
    int e = blockIdx.x * blockDim.x + threadIdx.x;
    if (e < NE) atomicAdd(&deg[dst[e]], 1);
}

__global__ __launch_bounds__(256) void deg_blocksum(const int* __restrict__ deg,
                                                    int* __restrict__ bsum)
{
    int i = blockIdx.x * 256 + threadIdx.x;
    int v = (i < NN) ? deg[i] : 0;
#pragma unroll
    for (int off = 32; off; off >>= 1) v += __shfl_xor(v, off);
    __shared__ int ws[4];
    if ((threadIdx.x & 63) == 0) ws[threadIdx.x >> 6] = v;
    __syncthreads();
    if (threadIdx.x == 0) bsum[blockIdx.x] = ws[0] + ws[1] + ws[2] + ws[3];
}

__global__ __launch_bounds__(256) void scan_bsum(int* __restrict__ bsum)
{
    __shared__ int tmp[256];
    int t = threadIdx.x;
    int orig = (t < NB) ? bsum[t] : 0;
    tmp[t] = orig;
    __syncthreads();
    for (int off = 1; off < 256; off <<= 1) {
        int v = (t >= off) ? tmp[t - off] : 0;
        __syncthreads();
        tmp[t] += v;
        __syncthreads();
    }
    if (t < NB) bsum[t] = tmp[t] - orig;  // exclusive prefix
}

__global__ __launch_bounds__(256) void write_rows(const int* __restrict__ deg,
                                                  const int* __restrict__ bpre,
                                                  int* __restrict__ row_start,
                                                  int* __restrict__ cursor)
{
    int i = blockIdx.x * 256 + threadIdx.x;
    int d = (i < NN) ? deg[i] : 0;
    int lane = threadIdx.x & 63, w = threadIdx.x >> 6;
    int x = d;
#pragma unroll
    for (int off = 1; off < 64; off <<= 1) {
        int v = __shfl_up(x, off);
        if (lane >= off) x += v;
    }
    __shared__ int wsum[4];
    if (lane == 63) wsum[w] = x;
    __syncthreads();
    int woff = 0;
#pragma unroll
    for (int k = 0; k < 4; ++k)
        if (k < w) woff += wsum[k];
    if (i < NN) {
        int rs = bpre[blockIdx.x] + woff + x - d;
        row_start[i] = rs;
        cursor[i] = rs;
    }
    if (blockIdx.x == 0 && threadIdx.x == 0) row_start[NN] = NE;
}

// cursor pre-initialized to row_start values -> absolute positions
__global__ void scatter_src(const int* __restrict__ src, const int* __restrict__ dst,
                            int* __restrict__ cursor, int* __restrict__ src_sorted)
{
    int e = blockIdx.x * blockDim.x + threadIdx.x;
    if (e < NE) {
        int pos = atomicAdd(&cursor[dst[e]], 1);
        src_sorted[pos] = src[e];
    }
}

// ---- Layer-1 fused, single pass, defer-max, 2-edge software pipeline.
//      block=node, wave=edges (stride 4), lane=4 contiguous dims (coalesced 1KB row).
__global__ __launch_bounds__(256) void gat1_fused(
    const float* __restrict__ hs, const float* __restrict__ hd,
    const float* __restrict__ attn, const int* __restrict__ src_sorted,
    const int* __restrict__ row_start,
    const float* __restrict__ W2s, const float* __restrict__ b2s,
    const float* __restrict__ W2d, const float* __restrict__ b2d,
    float* __restrict__ hs2, float* __restrict__ hd2)
{
    __shared__ float mw[4][4];       // [wave][head] deferred max
    __shared__ float denw[4][4];     // [wave][head] denominator
    __shared__ float4 accs[4][64];   // [wave][lane] accumulators

    const int n = blockIdx.x;
    const int tid = threadIdx.x;
    const int w = tid >> 6;
    const int lane = tid & 63;
    const int q = lane & 15;
    const int hh = lane >> 4;        // head owning this lane's 4 dims
    const int beg = row_start[n], end_ = row_start[n + 1];

    const float4 a4 = *reinterpret_cast<const float4*>(&attn[lane * 4]);
    const float4 y4 = *reinterpret_cast<const float4*>(&hd[(size_t)n * 256 + lane * 4]);

    float m = -INFINITY, den = 0.0f;
    float4 acc = make_float4(0.f, 0.f, 0.f, 0.f);

    int i = beg + w;
    // -------- pipelined pairs: edges (i, i+4) with independent gathers --------
    for (; i + 4 < end_; i += 8) {
        const int sa = __builtin_amdgcn_readfirstlane(src_sorted[i]);
        const int sb = __builtin_amdgcn_readfirstlane(src_sorted[i + 4]);
        const float4 xa = *reinterpret_cast<const float4*>(&hs[(size_t)sa * 256 + lane * 4]);
        const float4 xb = *reinterpret_cast<const float4*>(&hs[(size_t)sb * 256 + lane * 4]);
        float ta, tb, pa, pb;
        ta = xa.x + y4.x; ta = fmaxf(ta, NEG * ta); pa = ta * a4.x;
        tb = xb.x + y4.x; tb = fmaxf(tb, NEG * tb); pb = tb * a4.x;
        ta = xa.y + y4.y; ta = fmaxf(ta, NEG * ta); pa = fmaf(ta, a4.y, pa);
        tb = xb.y + y4.y; tb = fmaxf(tb, NEG * tb); pb = fmaf(tb, a4.y, pb);
        ta = xa.z + y4.z; ta = fmaxf(ta, NEG * ta); pa = fmaf(ta, a4.z, pa);
        tb = xb.z + y4.z; tb = fmaxf(tb, NEG * tb); pb = fmaf(tb, a4.z, pb);
        ta = xa.w + y4.w; ta = fmaxf(ta, NEG * ta); pa = fmaf(ta, a4.w, pa);
        tb = xb.w + y4.w; tb = fmaxf(tb, NEG * tb); pb = fmaf(tb, a4.w, pb);
        pa += __shfl_xor(pa, 1);  pb += __shfl_xor(pb, 1);
        pa += __shfl_xor(pa, 2);  pb += __shfl_xor(pb, 2);
        pa += __shfl_xor(pa, 4);  pb += __shfl_xor(pb, 4);
        pa += __shfl_xor(pa, 8);  pb += __shfl_xor(pb, 8);
        // sequential state update (a then b); rescale is rare (defer-max T13)
        if (pa > m + 8.0f) {
            const float rs = __expf(m - pa);  // first edge: exp(-inf)=0
            den *= rs;
            acc.x *= rs; acc.y *= rs; acc.z *= rs; acc.w *= rs;
            m = pa;
        }
        const float wa = __expf(pa - m);
        den += wa;
        acc.x = fmaf(wa, xa.x, acc.x);
        acc.y = fmaf(wa, xa.y, acc.y);
        acc.z = fmaf(wa, xa.z, acc.z);
        acc.w = fmaf(wa, xa.w, acc.w);
        if (pb > m + 8.0f) {
            const float rs = __expf(m - pb);
            den *= rs;
            acc.x *= rs; acc.y *= rs; acc.z *= rs; acc.w *= rs;
            m = pb;
        }
        const float wb = __expf(pb - m);
        den += wb;
        acc.x = fmaf(wb, xb.x, acc.x);
        acc.y = fmaf(wb, xb.y, acc.y);
        acc.z = fmaf(wb, xb.z, acc.z);
        acc.w = fmaf(wb, xb.w, acc.w);
    }
    // -------- tail (at most one edge for this wave) --------
    if (i < end_) {
        const int s = __builtin_amdgcn_readfirstlane(src_sorted[i]);
        const float4 x = *reinterpret_cast<const float4*>(&hs[(size_t)s * 256 + lane * 4]);
        float t, p;
        t = x.x + y4.x; t = fmaxf(t, NEG * t); p  = t * a4.x;
        t = x.y + y4.y; t = fmaxf(t, NEG * t); p = fmaf(t, a4.y, p);
        t = x.z + y4.z; t = fmaxf(t, NEG * t); p = fmaf(t, a4.z, p);
        t = x.w + y4.w; t = fmaxf(t, NEG * t); p = fmaf(t, a4.w, p);
        p += __shfl_xor(p, 1);
        p += __shfl_xor(p, 2);
        p += __shfl_xor(p, 4);
        p += __shfl_xor(p, 8);
        if (p > m + 8.0f) {
            const float rs = __expf(m - p);
            den *= rs;
            acc.x *= rs; acc.y *= rs; acc.z *= rs; acc.w *= rs;
            m = p;
        }
        const float wv = __expf(p - m);
        den += wv;
        acc.x = fmaf(wv, x.x, acc.x);
        acc.y = fmaf(wv, x.y, acc.y);
        acc.z = fmaf(wv, x.z, acc.z);
        acc.w = fmaf(wv, x.w, acc.w);
    }

    if (q == 0) { mw[w][hh] = m; denw[w][hh] = den; }
    accs[w][lane] = acc;
    __syncthreads();

    if (w == 0) {
        // per-head global max across waves
        const float m0 = mw[0][hh], m1 = mw[1][hh], m2v = mw[2][hh], m3 = mw[3][hh];
        const float M = fmaxf(fmaxf(m0, m1), fmaxf(m2v, m3));
        float4 o = make_float4(0.f, 0.f, 0.f, 0.f);
        float dtot = 0.0f;
#pragma unroll
        for (int k = 0; k < 4; ++k) {
            const float mk = mw[k][hh];
            const float sc = (mk == -INFINITY) ? 0.0f : __expf(mk - M);
            dtot = fmaf(denw[k][hh], sc, dtot);
            const float4 av = accs[k][lane];
            o.x = fmaf(av.x, sc, o.x);
            o.y = fmaf(av.y, sc, o.y);
            o.z = fmaf(av.z, sc, o.z);
            o.w = fmaf(av.w, sc, o.w);
        }
        const float inv = (dtot > 0.0f) ? 1.0f / dtot : 0.0f;
        o.x *= inv; o.y *= inv; o.z *= inv; o.w *= inv;
        // ELU
        o.x = (o.x > 0.0f) ? o.x : __expf(o.x) - 1.0f;
        o.y = (o.y > 0.0f) ? o.y : __expf(o.y) - 1.0f;
        o.z = (o.z > 0.0f) ? o.z : __expf(o.z) - 1.0f;
        o.w = (o.w > 0.0f) ? o.w : __expf(o.w) - 1.0f;
        // fused layer-2 projection: rows 4*lane..4*lane+3 of W2 [256][2]
        const float4 wsa = *reinterpret_cast<const float4*>(&W2s[lane * 8]);
        const float4 wsb = *reinterpret_cast<const float4*>(&W2s[lane * 8 + 4]);
        const float4 wda = *reinterpret_cast<const float4*>(&W2d[lane * 8]);
        const float4 wdb = *reinterpret_cast<const float4*>(&W2d[lane * 8 + 4]);
        float ps0 = o.x * wsa.x + o.y * wsa.z + o.z * wsb.x + o.w * wsb.z;
        float ps1 = o.x * wsa.y + o.y * wsa.w + o.z * wsb.y + o.w * wsb.w;
        float pd0 = o.x * wda.x + o.y * wda.z + o.z * wdb.x + o.w * wdb.z;
        float pd1 = o.x * wda.y + o.y * wda.w + o.z * wdb.y + o.w * wdb.w;
#pragma unroll
        for (int off = 32; off; off >>= 1) {
            ps0 += __shfl_xor(ps0, off);
            ps1 += __shfl_xor(ps1, off);
            pd0 += __shfl_xor(pd0, off);
            pd1 += __shfl_xor(pd1, off);
        }
        if (lane == 0) {
            hs2[(size_t)n * 2 + 0] = ps0 + b2s[0];
            hs2[(size_t)n * 2 + 1] = ps1 + b2s[1];
            hd2[(size_t)n * 2 + 0] = pd0 + b2d[0];
            hd2[(size_t)n * 2 + 1] = pd1 + b2d[1];
        }
    }
}

// ---------------- Layer-2: 16 lanes per node (deg ~16), 16 nodes per block ----
__global__ __launch_bounds__(256) void node2_kernel(
    const float* __restrict__ hs2, const float* __restrict__ hd2,
    const float* __restrict__ attn2, const int* __restrict__ src_sorted,
    const int* __restrict__ row_start, float* __restrict__ out)
{
    const int n = blockIdx.x * 16 + (threadIdx.x >> 4);
    const int q = threadIdx.x & 15;
    if (n >= NN) return;
    const float a0 = attn2[0], a1 = attn2[1];
    const float h0 = hd2[n * 2 + 0], h1v = hd2[n * 2 + 1];
    const int beg = row_start[n], end_ = row_start[n + 1];
    float m = -INFINITY, den = 0.0f, A0 = 0.0f, A1 = 0.0f;
    for (int i = beg + q; i < end_; i += 16) {
        const int s = src_sorted[i];
        float x0 = hs2[s * 2 + 0], x1 = hs2[s * 2 + 1];
        float t0 = x0 + h0;  t0 = fmaxf(t0, NEG * t0);
        float t1 = x1 + h1v; t1 = fmaxf(t1, NEG * t1);
        float p = fmaf(t0, a0, t1 * a1);
        float mn = fmaxf(m, p);
        float c = __expf(m - mn);
        float w = __expf(p - mn);
        den = den * c + w;
        A0 = A0 * c + w * x0;
        A1 = A1 * c + w * x1;
        m = mn;
    }
#pragma unroll
    for (int off = 1; off < 16; off <<= 1) {
        float m2 = __shfl_xor(m, off, 16);
        float d2 = __shfl_xor(den, off, 16);
        float b0 = __shfl_xor(A0, off, 16);
        float b1 = __shfl_xor(A1, off, 16);
        float mn = fmaxf(m, m2);
        float c1 = (m < mn) ? __expf(m - mn) : 1.0f;
        float c2 = (m2 < mn) ? __expf(m2 - mn) : 1.0f;
        den = den * c1 + d2 * c2;
        A0 = A0 * c1 + b0 * c2;
        A1 = A1 * c1 + b1 * c2;
        m = mn;
    }
    if (q == 0) {
        out[n * 2 + 0] = (den > 0.0f) ? A0 / den : 0.0f;
        out[n * 2 + 1] = (den > 0.0f) ? A1 / den : 0.0f;
    }
}

// ---------------- launch ----------------
extern "C" void kernel_launch(void* const* d_in, const int* in_sizes, int n_in,
                              void* d_out, int out_size, void* d_ws, size_t ws_size,
                              hipStream_t stream)
{
    const float* feat  = (const float*)d_in[0];
    const int*   src   = (const int*)d_in[1];
    const int*   dst   = (const int*)d_in[2];
    const float* W1s   = (const float*)d_in[3];
    const float* b1s   = (const float*)d_in[4];
    const float* W1d   = (const float*)d_in[5];
    const float* b1d   = (const float*)d_in[6];
    const float* attn1 = (const float*)d_in[7];
    const float* W2s   = (const float*)d_in[8];
    const float* b2s   = (const float*)d_in[9];
    const float* W2d   = (const float*)d_in[10];
    const float* b2d   = (const float*)d_in[11];
    const float* attn2 = (const float*)d_in[12];
    float* out = (float*)d_out;

    char* ws = (char*)d_ws;
    size_t off = 0;
    auto alloc = [&](size_t bytes) {
        char* p = ws + off;
        off += (bytes + 255) & ~size_t(255);
        return p;
    };
    float* hs1        = (float*)alloc((size_t)NN * 256 * 4);
    float* hd1        = (float*)alloc((size_t)NN * 256 * 4);
    int*   src_sorted = (int*)alloc((size_t)NE * 4);
    int*   row_start  = (int*)alloc((size_t)(NN + 1) * 4);
    int*   deg        = (int*)alloc((size_t)NN * 4);
    int*   cursor     = (int*)alloc((size_t)NN * 4);
    int*   bsum       = (int*)alloc((size_t)NB * 4);
    float* hs2        = (float*)alloc((size_t)NN * 2 * 4);
    float* hd2        = (float*)alloc((size_t)NN * 2 * 4);
    (void)ws_size; (void)n_in; (void)in_sizes; (void)out_size;

    hipMemsetAsync(deg, 0, (size_t)NN * 4, stream);

    dim3 ggrid((NN + 63) / 64, 2);
    gemm_proj<<<ggrid, 256, 0, stream>>>(feat, W1s, b1s, hs1, W1d, b1d, hd1, NN);

    const int eb = (NE + 255) / 256;
    count_deg<<<eb, 256, 0, stream>>>(dst, deg);
    deg_blocksum<<<NB, 256, 0, stream>>>(deg, bsum);
    scan_bsum<<<1, 256, 0, stream>>>(bsum);
    write_rows<<<NB, 256, 0, stream>>>(deg, bsum, row_start, cursor);
    scatter_src<<<eb, 256, 0, stream>>>(src, dst, cursor, src_sorted);

    gat1_fused<<<NN, 256, 0, stream>>>(hs1, hd1, attn1, src_sorted, row_start,
                                       W2s, b2s, W2d, b2d, hs2, hd2);

    node2_kernel<<<(NN + 15) / 16, 256, 0, stream>>>(hs2, hd2, attn2, src_sorted,
                                                     row_start, out);
}

// Round 10
// 317.461 us; speedup vs baseline: 1.1500x; 1.1500x over previous
//
#include <hip/hip_runtime.h>
#include <math.h>

#define NN 50000
#define NE 800000
#define NEG 0.2f
#define NB 196  // ceil(NN/256)

// ---------- fused dual GEMM: out[N,256] = feat[N,128] @ W + b  (gridDim.y picks W1s/W1d)
// 16-k chunked: fT[64][16] (4KB) + k-transposed wTt[4][256][4] (16KB); all ds_read_b128.
__global__ __launch_bounds__(256) void gemm_proj(
    const float* __restrict__ feat,
    const float* __restrict__ Wa, const float* __restrict__ ba, float* __restrict__ outa,
    const float* __restrict__ Wb, const float* __restrict__ bb, float* __restrict__ outb,
    int n_rows)
{
    const float* W  = blockIdx.y ? Wb : Wa;
    const float* bv = blockIdx.y ? bb : ba;
    float* out      = blockIdx.y ? outb : outa;

    __shared__ float fT[64][16];      // feat k-chunk
    __shared__ float wTt[4][256][4];  // [g][col][j], k = k0 + 4g + j

    const int tid  = threadIdx.x;
    const int w    = tid >> 6;        // wave 0..3 -> rows w*16..w*16+15
    const int tn   = tid & 63;        // col = tn + ci*64
    const int row0 = blockIdx.x * 64;

    float acc[16][4];
#pragma unroll
    for (int ri = 0; ri < 16; ++ri)
#pragma unroll
        for (int ci = 0; ci < 4; ++ci) acc[ri][ci] = 0.0f;

    const int fr = tid >> 2, fj = tid & 3;   // feat stage mapping
    const int sg = tid >> 8, scol = tid & 255; (void)sg;

    for (int c8 = 0; c8 < 8; ++c8) {
        const int k0 = c8 * 16;
        // ---- issue global loads into regs (latency hides under previous compute) ----
        int grow = row0 + fr; if (grow >= n_rows) grow = n_rows - 1;
        const float4 fv = *reinterpret_cast<const float4*>(
            &feat[(size_t)grow * 128 + k0 + fj * 4]);
        float wv[4];
#pragma unroll
        for (int j = 0; j < 4; ++j)
            wv[j] = W[(size_t)(k0 + 0 * 4 + j) * 256 + scol];
        float wv1[4], wv2[4], wv3[4];
#pragma unroll
        for (int j = 0; j < 4; ++j) wv1[j] = W[(size_t)(k0 + 1 * 4 + j) * 256 + scol];
#pragma unroll
        for (int j = 0; j < 4; ++j) wv2[j] = W[(size_t)(k0 + 2 * 4 + j) * 256 + scol];
#pragma unroll
        for (int j = 0; j < 4; ++j) wv3[j] = W[(size_t)(k0 + 3 * 4 + j) * 256 + scol];

        __syncthreads();  // previous chunk fully consumed
        *reinterpret_cast<float4*>(&fT[fr][fj * 4]) = fv;
        *reinterpret_cast<float4*>(&wTt[0][scol][0]) = make_float4(wv[0], wv[1], wv[2], wv[3]);
        *reinterpret_cast<float4*>(&wTt[1][scol][0]) = make_float4(wv1[0], wv1[1], wv1[2], wv1[3]);
        *reinterpret_cast<float4*>(&wTt[2][scol][0]) = make_float4(wv2[0], wv2[1], wv2[2], wv2[3]);
        *reinterpret_cast<float4*>(&wTt[3][scol][0]) = make_float4(wv3[0], wv3[1], wv3[2], wv3[3]);
        __syncthreads();

        // ---- compute: per g, 4 w-reads + 16 broadcast a-reads -> 256 quad-FMAs ----
#pragma unroll
        for (int g = 0; g < 4; ++g) {
            float4 w4[4];
#pragma unroll
            for (int ci = 0; ci < 4; ++ci)
                w4[ci] = *reinterpret_cast<const float4*>(&wTt[g][tn + ci * 64][0]);
#pragma unroll
            for (int ri = 0; ri < 16; ++ri) {
                const float4 aq = *reinterpret_cast<const float4*>(&fT[w * 16 + ri][g * 4]);
#pragma unroll
                for (int ci = 0; ci < 4; ++ci) {
                    acc[ri][ci] = fmaf(aq.x, w4[ci].x, acc[ri][ci]);
                    acc[ri][ci] = fmaf(aq.y, w4[ci].y, acc[ri][ci]);
                    acc[ri][ci] = fmaf(aq.z, w4[ci].z, acc[ri][ci]);
                    acc[ri][ci] = fmaf(aq.w, w4[ci].w, acc[ri][ci]);
                }
            }
        }
    }

    float bvv[4];
#pragma unroll
    for (int ci = 0; ci < 4; ++ci) bvv[ci] = bv[tn + ci * 64];
#pragma unroll
    for (int ri = 0; ri < 16; ++ri) {
        const int row = row0 + w * 16 + ri;
        if (row < n_rows) {
#pragma unroll
            for (int ci = 0; ci < 4; ++ci)
                out[(size_t)row * 256 + tn + ci * 64] = acc[ri][ci] + bvv[ci];
        }
    }
}

// ---------------- CSR build ----------------
__global__ void count_deg(const int* __restrict__ dst, int* __restrict__ deg)
{
    int e = blockIdx.x * blockDim.x + threadIdx.x;
    if (e < NE) atomicAdd(&deg[dst[e]], 1);
}

__global__ __launch_bounds__(256) void deg_blocksum(const int* __restrict__ deg,
                                                    int* __restrict__ bsum)
{
    int i = blockIdx.x * 256 + threadIdx.x;
    int v = (i < NN) ? deg[i] : 0;
#pragma unroll
    for (int off = 32; off; off >>= 1) v += __shfl_xor(v, off);
    __shared__ int ws[4];
    if ((threadIdx.x & 63) == 0) ws[threadIdx.x >> 6] = v;
    __syncthreads();
    if (threadIdx.x == 0) bsum[blockIdx.x] = ws[0] + ws[1] + ws[2] + ws[3];
}

__global__ __launch_bounds__(256) void scan_bsum(int* __restrict__ bsum)
{
    __shared__ int tmp[256];
    int t = threadIdx.x;
    int orig = (t < NB) ? bsum[t] : 0;
    tmp[t] = orig;
    __syncthreads();
    for (int off = 1; off < 256; off <<= 1) {
        int v = (t >= off) ? tmp[t - off] : 0;
        __syncthreads();
        tmp[t] += v;
        __syncthreads();
    }
    if (t < NB) bsum[t] = tmp[t] - orig;  // exclusive prefix
}

__global__ __launch_bounds__(256) void write_rows(const int* __restrict__ deg,
                                                  const int* __restrict__ bpre,
                                                  int* __restrict__ row_start,
                                                  int* __restrict__ cursor)
{
    int i = blockIdx.x * 256 + threadIdx.x;
    int d = (i < NN) ? deg[i] : 0;
    int lane = threadIdx.x & 63, w = threadIdx.x >> 6;
    int x = d;
#pragma unroll
    for (int off = 1; off < 64; off <<= 1) {
        int v = __shfl_up(x, off);
        if (lane >= off) x += v;
    }
    __shared__ int wsum[4];
    if (lane == 63) wsum[w] = x;
    __syncthreads();
    int woff = 0;
#pragma unroll
    for (int k = 0; k < 4; ++k)
        if (k < w) woff += wsum[k];
    if (i < NN) {
        int rs = bpre[blockIdx.x] + woff + x - d;
        row_start[i] = rs;
        cursor[i] = rs;
    }
    if (blockIdx.x == 0 && threadIdx.x == 0) row_start[NN] = NE;
}

// cursor pre-initialized to row_start values -> absolute positions
__global__ void scatter_src(const int* __restrict__ src, const int* __restrict__ dst,
                            int* __restrict__ cursor, int* __restrict__ src_sorted)
{
    int e = blockIdx.x * blockDim.x + threadIdx.x;
    if (e < NE) {
        int pos = atomicAdd(&cursor[dst[e]], 1);
        src_sorted[pos] = src[e];
    }
}

// ---- Layer-1 fused, single pass, defer-max, 2-edge software pipeline.
//      block=node, wave=edges (stride 4), lane=4 contiguous dims (coalesced 1KB row).
__global__ __launch_bounds__(256) void gat1_fused(
    const float* __restrict__ hs, const float* __restrict__ hd,
    const float* __restrict__ attn, const int* __restrict__ src_sorted,
    const int* __restrict__ row_start,
    const float* __restrict__ W2s, const float* __restrict__ b2s,
    const float* __restrict__ W2d, const float* __restrict__ b2d,
    float* __restrict__ hs2, float* __restrict__ hd2)
{
    __shared__ float mw[4][4];       // [wave][head] deferred max
    __shared__ float denw[4][4];     // [wave][head] denominator
    __shared__ float4 accs[4][64];   // [wave][lane] accumulators

    const int n = blockIdx.x;
    const int tid = threadIdx.x;
    const int w = tid >> 6;
    const int lane = tid & 63;
    const int q = lane & 15;
    const int hh = lane >> 4;        // head owning this lane's 4 dims
    const int beg = row_start[n], end_ = row_start[n + 1];

    const float4 a4 = *reinterpret_cast<const float4*>(&attn[lane * 4]);
    const float4 y4 = *reinterpret_cast<const float4*>(&hd[(size_t)n * 256 + lane * 4]);

    float m = -INFINITY, den = 0.0f;
    float4 acc = make_float4(0.f, 0.f, 0.f, 0.f);

    int i = beg + w;
    // -------- pipelined pairs: edges (i, i+4) with independent gathers --------
    for (; i + 4 < end_; i += 8) {
        const int sa = __builtin_amdgcn_readfirstlane(src_sorted[i]);
        const int sb = __builtin_amdgcn_readfirstlane(src_sorted[i + 4]);
        const float4 xa = *reinterpret_cast<const float4*>(&hs[(size_t)sa * 256 + lane * 4]);
        const float4 xb = *reinterpret_cast<const float4*>(&hs[(size_t)sb * 256 + lane * 4]);
        float ta, tb, pa, pb;
        ta = xa.x + y4.x; ta = fmaxf(ta, NEG * ta); pa = ta * a4.x;
        tb = xb.x + y4.x; tb = fmaxf(tb, NEG * tb); pb = tb * a4.x;
        ta = xa.y + y4.y; ta = fmaxf(ta, NEG * ta); pa = fmaf(ta, a4.y, pa);
        tb = xb.y + y4.y; tb = fmaxf(tb, NEG * tb); pb = fmaf(tb, a4.y, pb);
        ta = xa.z + y4.z; ta = fmaxf(ta, NEG * ta); pa = fmaf(ta, a4.z, pa);
        tb = xb.z + y4.z; tb = fmaxf(tb, NEG * tb); pb = fmaf(tb, a4.z, pb);
        ta = xa.w + y4.w; ta = fmaxf(ta, NEG * ta); pa = fmaf(ta, a4.w, pa);
        tb = xb.w + y4.w; tb = fmaxf(tb, NEG * tb); pb = fmaf(tb, a4.w, pb);
        pa += __shfl_xor(pa, 1);  pb += __shfl_xor(pb, 1);
        pa += __shfl_xor(pa, 2);  pb += __shfl_xor(pb, 2);
        pa += __shfl_xor(pa, 4);  pb += __shfl_xor(pb, 4);
        pa += __shfl_xor(pa, 8);  pb += __shfl_xor(pb, 8);
        // sequential state update (a then b); rescale is rare (defer-max T13)
        if (pa > m + 8.0f) {
            const float rs = __expf(m - pa);  // first edge: exp(-inf)=0
            den *= rs;
            acc.x *= rs; acc.y *= rs; acc.z *= rs; acc.w *= rs;
            m = pa;
        }
        const float wa = __expf(pa - m);
        den += wa;
        acc.x = fmaf(wa, xa.x, acc.x);
        acc.y = fmaf(wa, xa.y, acc.y);
        acc.z = fmaf(wa, xa.z, acc.z);
        acc.w = fmaf(wa, xa.w, acc.w);
        if (pb > m + 8.0f) {
            const float rs = __expf(m - pb);
            den *= rs;
            acc.x *= rs; acc.y *= rs; acc.z *= rs; acc.w *= rs;
            m = pb;
        }
        const float wb = __expf(pb - m);
        den += wb;
        acc.x = fmaf(wb, xb.x, acc.x);
        acc.y = fmaf(wb, xb.y, acc.y);
        acc.z = fmaf(wb, xb.z, acc.z);
        acc.w = fmaf(wb, xb.w, acc.w);
    }
    // -------- tail (at most one edge for this wave) --------
    if (i < end_) {
        const int s = __builtin_amdgcn_readfirstlane(src_sorted[i]);
        const float4 x = *reinterpret_cast<const float4*>(&hs[(size_t)s * 256 + lane * 4]);
        float t, p;
        t = x.x + y4.x; t = fmaxf(t, NEG * t); p  = t * a4.x;
        t = x.y + y4.y; t = fmaxf(t, NEG * t); p = fmaf(t, a4.y, p);
        t = x.z + y4.z; t = fmaxf(t, NEG * t); p = fmaf(t, a4.z, p);
        t = x.w + y4.w; t = fmaxf(t, NEG * t); p = fmaf(t, a4.w, p);
        p += __shfl_xor(p, 1);
        p += __shfl_xor(p, 2);
        p += __shfl_xor(p, 4);
        p += __shfl_xor(p, 8);
        if (p > m + 8.0f) {
            const float rs = __expf(m - p);
            den *= rs;
            acc.x *= rs; acc.y *= rs; acc.z *= rs; acc.w *= rs;
            m = p;
        }
        const float wv = __expf(p - m);
        den += wv;
        acc.x = fmaf(wv, x.x, acc.x);
        acc.y = fmaf(wv, x.y, acc.y);
        acc.z = fmaf(wv, x.z, acc.z);
        acc.w = fmaf(wv, x.w, acc.w);
    }

    if (q == 0) { mw[w][hh] = m; denw[w][hh] = den; }
    accs[w][lane] = acc;
    __syncthreads();

    if (w == 0) {
        // per-head global max across waves
        const float m0 = mw[0][hh], m1 = mw[1][hh], m2v = mw[2][hh], m3 = mw[3][hh];
        const float M = fmaxf(fmaxf(m0, m1), fmaxf(m2v, m3));
        float4 o = make_float4(0.f, 0.f, 0.f, 0.f);
        float dtot = 0.0f;
#pragma unroll
        for (int k = 0; k < 4; ++k) {
            const float mk = mw[k][hh];
            const float sc = (mk == -INFINITY) ? 0.0f : __expf(mk - M);
            dtot = fmaf(denw[k][hh], sc, dtot);
            const float4 av = accs[k][lane];
            o.x = fmaf(av.x, sc, o.x);
            o.y = fmaf(av.y, sc, o.y);
            o.z = fmaf(av.z, sc, o.z);
            o.w = fmaf(av.w, sc, o.w);
        }
        const float inv = (dtot > 0.0f) ? 1.0f / dtot : 0.0f;
        o.x *= inv; o.y *= inv; o.z *= inv; o.w *= inv;
        // ELU
        o.x = (o.x > 0.0f) ? o.x : __expf(o.x) - 1.0f;
        o.y = (o.y > 0.0f) ? o.y : __expf(o.y) - 1.0f;
        o.z = (o.z > 0.0f) ? o.z : __expf(o.z) - 1.0f;
        o.w = (o.w > 0.0f) ? o.w : __expf(o.w) - 1.0f;
        // fused layer-2 projection: rows 4*lane..4*lane+3 of W2 [256][2]
        const float4 wsa = *reinterpret_cast<const float4*>(&W2s[lane * 8]);
        const float4 wsb = *reinterpret_cast<const float4*>(&W2s[lane * 8 + 4]);
        const float4 wda = *reinterpret_cast<const float4*>(&W2d[lane * 8]);
        const float4 wdb = *reinterpret_cast<const float4*>(&W2d[lane * 8 + 4]);
        float ps0 = o.x * wsa.x + o.y * wsa.z + o.z * wsb.x + o.w * wsb.z;
        float ps1 = o.x * wsa.y + o.y * wsa.w + o.z * wsb.y + o.w * wsb.w;
        float pd0 = o.x * wda.x + o.y * wda.z + o.z * wdb.x + o.w * wdb.z;
        float pd1 = o.x * wda.y + o.y * wda.w + o.z * wdb.y + o.w * wdb.w;
#pragma unroll
        for (int off = 32; off; off >>= 1) {
            ps0 += __shfl_xor(ps0, off);
            ps1 += __shfl_xor(ps1, off);
            pd0 += __shfl_xor(pd0, off);
            pd1 += __shfl_xor(pd1, off);
        }
        if (lane == 0) {
            hs2[(size_t)n * 2 + 0] = ps0 + b2s[0];
            hs2[(size_t)n * 2 + 1] = ps1 + b2s[1];
            hd2[(size_t)n * 2 + 0] = pd0 + b2d[0];
            hd2[(size_t)n * 2 + 1] = pd1 + b2d[1];
        }
    }
}

// ---------------- Layer-2: 16 lanes per node (deg ~16), 16 nodes per block ----
__global__ __launch_bounds__(256) void node2_kernel(
    const float* __restrict__ hs2, const float* __restrict__ hd2,
    const float* __restrict__ attn2, const int* __restrict__ src_sorted,
    const int* __restrict__ row_start, float* __restrict__ out)
{
    const int n = blockIdx.x * 16 + (threadIdx.x >> 4);
    const int q = threadIdx.x & 15;
    if (n >= NN) return;
    const float a0 = attn2[0], a1 = attn2[1];
    const float h0 = hd2[n * 2 + 0], h1v = hd2[n * 2 + 1];
    const int beg = row_start[n], end_ = row_start[n + 1];
    float m = -INFINITY, den = 0.0f, A0 = 0.0f, A1 = 0.0f;
    for (int i = beg + q; i < end_; i += 16) {
        const int s = src_sorted[i];
        float x0 = hs2[s * 2 + 0], x1 = hs2[s * 2 + 1];
        float t0 = x0 + h0;  t0 = fmaxf(t0, NEG * t0);
        float t1 = x1 + h1v; t1 = fmaxf(t1, NEG * t1);
        float p = fmaf(t0, a0, t1 * a1);
        float mn = fmaxf(m, p);
        float c = __expf(m - mn);
        float w = __expf(p - mn);
        den = den * c + w;
        A0 = A0 * c + w * x0;
        A1 = A1 * c + w * x1;
        m = mn;
    }
#pragma unroll
    for (int off = 1; off < 16; off <<= 1) {
        float m2 = __shfl_xor(m, off, 16);
        float d2 = __shfl_xor(den, off, 16);
        float b0 = __shfl_xor(A0, off, 16);
        float b1 = __shfl_xor(A1, off, 16);
        float mn = fmaxf(m, m2);
        float c1 = (m < mn) ? __expf(m - mn) : 1.0f;
        float c2 = (m2 < mn) ? __expf(m2 - mn) : 1.0f;
        den = den * c1 + d2 * c2;
        A0 = A0 * c1 + b0 * c2;
        A1 = A1 * c1 + b1 * c2;
        m = mn;
    }
    if (q == 0) {
        out[n * 2 + 0] = (den > 0.0f) ? A0 / den : 0.0f;
        out[n * 2 + 1] = (den > 0.0f) ? A1 / den : 0.0f;
    }
}

// ---------------- launch ----------------
extern "C" void kernel_launch(void* const* d_in, const int* in_sizes, int n_in,
                              void* d_out, int out_size, void* d_ws, size_t ws_size,
                              hipStream_t stream)
{
    const float* feat  = (const float*)d_in[0];
    const int*   src   = (const int*)d_in[1];
    const int*   dst   = (const int*)d_in[2];
    const float* W1s   = (const float*)d_in[3];
    const float* b1s   = (const float*)d_in[4];
    const float* W1d   = (const float*)d_in[5];
    const float* b1d   = (const float*)d_in[6];
    const float* attn1 = (const float*)d_in[7];
    const float* W2s   = (const float*)d_in[8];
    const float* b2s   = (const float*)d_in[9];
    const float* W2d   = (const float*)d_in[10];
    const float* b2d   = (const float*)d_in[11];
    const float* attn2 = (const float*)d_in[12];
    float* out = (float*)d_out;

    char* ws = (char*)d_ws;
    size_t off = 0;
    auto alloc = [&](size_t bytes) {
        char* p = ws + off;
        off += (bytes + 255) & ~size_t(255);
        return p;
    };
    float* hs1        = (float*)alloc((size_t)NN * 256 * 4);
    float* hd1        = (float*)alloc((size_t)NN * 256 * 4);
    int*   src_sorted = (int*)alloc((size_t)NE * 4);
    int*   row_start  = (int*)alloc((size_t)(NN + 1) * 4);
    int*   deg        = (int*)alloc((size_t)NN * 4);
    int*   cursor     = (int*)alloc((size_t)NN * 4);
    int*   bsum       = (int*)alloc((size_t)NB * 4);
    float* hs2        = (float*)alloc((size_t)NN * 2 * 4);
    float* hd2        = (float*)alloc((size_t)NN * 2 * 4);
    (void)ws_size; (void)n_in; (void)in_sizes; (void)out_size;

    hipMemsetAsync(deg, 0, (size_t)NN * 4, stream);

    dim3 ggrid((NN + 63) / 64, 2);
    gemm_proj<<<ggrid, 256, 0, stream>>>(feat, W1s, b1s, hs1, W1d, b1d, hd1, NN);

    const int eb = (NE + 255) / 256;
    count_deg<<<eb, 256, 0, stream>>>(dst, deg);
    deg_blocksum<<<NB, 256, 0, stream>>>(deg, bsum);
    scan_bsum<<<1, 256, 0, stream>>>(bsum);
    write_rows<<<NB, 256, 0, stream>>>(deg, bsum, row_start, cursor);
    scatter_src<<<eb, 256, 0, stream>>>(src, dst, cursor, src_sorted);

    gat1_fused<<<NN, 256, 0, stream>>>(hs1, hd1, attn1, src_sorted, row_start,
                                       W2s, b2s, W2d, b2d, hs2, hd2);

    node2_kernel<<<(NN + 15) / 16, 256, 0, stream>>>(hs2, hd2, attn2, src_sorted,
                                                     row_start, out);
}

// Round 11
// 290.597 us; speedup vs baseline: 1.2563x; 1.0924x over previous
//
#include <hip/hip_runtime.h>
#include <math.h>

#define NN 50000
#define NE 800000
#define NEG 0.2f
#define NB 196  // ceil(NN/256)

typedef __attribute__((ext_vector_type(8))) short bf16x8;
typedef __attribute__((ext_vector_type(4))) float f32x4;

__device__ __forceinline__ unsigned short bf16_rne(float x)
{
    unsigned u = __float_as_uint(x);
    return (unsigned short)((u + 0x7FFF + ((u >> 16) & 1)) >> 16);
}
__device__ __forceinline__ float bf16_to_f(unsigned short h)
{
    return __uint_as_float(((unsigned)h) << 16);
}

// ---- split feat f32 -> hi/lo bf16 (row-major [N][128]) ----
__global__ __launch_bounds__(256) void cvt_feat(
    const float* __restrict__ f, unsigned short* __restrict__ hi,
    unsigned short* __restrict__ lo)
{
    const int i = blockIdx.x * 256 + threadIdx.x;   // one float4 per thread
    if (i >= NN * 128 / 4) return;
    const float4 v = reinterpret_cast<const float4*>(f)[i];
    ushort4 h, l;
    h.x = bf16_rne(v.x); l.x = bf16_rne(v.x - bf16_to_f(h.x));
    h.y = bf16_rne(v.y); l.y = bf16_rne(v.y - bf16_to_f(h.y));
    h.z = bf16_rne(v.z); l.z = bf16_rne(v.z - bf16_to_f(h.z));
    h.w = bf16_rne(v.w); l.w = bf16_rne(v.w - bf16_to_f(h.w));
    reinterpret_cast<ushort4*>(hi)[i] = h;
    reinterpret_cast<ushort4*>(lo)[i] = l;
}

// ---- repack W [128][256] f32 -> MFMA fragment order [ks][ct][lane][8], hi/lo bf16 ----
__global__ __launch_bounds__(256) void cvt_w(
    const float* __restrict__ Ws, const float* __restrict__ Wd,
    unsigned short* __restrict__ ShiP, unsigned short* __restrict__ SloP,
    unsigned short* __restrict__ DhiP, unsigned short* __restrict__ DloP)
{
    const int idx = blockIdx.x * 256 + threadIdx.x;   // 0..32767
    const float* W = blockIdx.y ? Wd : Ws;
    unsigned short* oh = blockIdx.y ? DhiP : ShiP;
    unsigned short* ol = blockIdx.y ? DloP : SloP;
    const int j  = idx & 7;
    const int l  = (idx >> 3) & 63;
    const int ct = (idx >> 9) & 15;
    const int ks = idx >> 13;
    const int k   = ks * 32 + ((l >> 4) << 3) + j;
    const int col = (ct << 4) + (l & 15);
    const float x = W[(size_t)k * 256 + col];
    const unsigned short h = bf16_rne(x);
    oh[idx] = h;
    ol[idx] = bf16_rne(x - bf16_to_f(h));
}

// ---- dual GEMM on matrix cores: out[N,256] = feat[N,128] @ W + b (split-bf16, 3 terms)
__global__ __launch_bounds__(256) void gemm_mfma(
    const unsigned short* __restrict__ fhi, const unsigned short* __restrict__ flo,
    const unsigned short* __restrict__ WhS, const unsigned short* __restrict__ WlS,
    const float* __restrict__ bS, float* __restrict__ outS,
    const unsigned short* __restrict__ WhD, const unsigned short* __restrict__ WlD,
    const float* __restrict__ bD, float* __restrict__ outD)
{
    const unsigned short* Wh = blockIdx.y ? WhD : WhS;
    const unsigned short* Wl = blockIdx.y ? WlD : WlS;
    const float* bv = blockIdx.y ? bD : bS;
    float* out      = blockIdx.y ? outD : outS;

    const int tid = threadIdx.x;
    const int w   = tid >> 6;        // wave -> rows w*16..+15
    const int l   = tid & 63;
    const int r16 = l & 15;          // A row within tile
    const int kg  = l >> 4;          // k-group (8 wide)
    const int row0 = blockIdx.x * 64;

    int arow = row0 + w * 16 + r16;
    if (arow >= NN) arow = NN - 1;   // clamp (stores guarded)

    f32x4 acc[16];
#pragma unroll
    for (int ct = 0; ct < 16; ++ct) acc[ct] = (f32x4){0.f, 0.f, 0.f, 0.f};

#pragma unroll
    for (int ks = 0; ks < 4; ++ks) {
        const bf16x8 ah = *reinterpret_cast<const bf16x8*>(
            &fhi[(size_t)arow * 128 + ks * 32 + kg * 8]);
        const bf16x8 al = *reinterpret_cast<const bf16x8*>(
            &flo[(size_t)arow * 128 + ks * 32 + kg * 8]);
#pragma unroll
        for (int ct = 0; ct < 16; ++ct) {
            const size_t boff = ((size_t)(ks * 16 + ct) * 64 + l) * 8;
            const bf16x8 bh = *reinterpret_cast<const bf16x8*>(&Wh[boff]);
            const bf16x8 bl = *reinterpret_cast<const bf16x8*>(&Wl[boff]);
            acc[ct] = __builtin_amdgcn_mfma_f32_16x16x32_bf16(ah, bh, acc[ct], 0, 0, 0);
            acc[ct] = __builtin_amdgcn_mfma_f32_16x16x32_bf16(ah, bl, acc[ct], 0, 0, 0);
            acc[ct] = __builtin_amdgcn_mfma_f32_16x16x32_bf16(al, bh, acc[ct], 0, 0, 0);
        }
    }

    // D layout: col = ct*16 + (lane&15), row = w*16 + (lane>>4)*4 + reg
    const int orow0 = row0 + w * 16 + kg * 4;
#pragma unroll
    for (int ct = 0; ct < 16; ++ct) {
        const int col = ct * 16 + r16;
        const float bias = bv[col];
#pragma unroll
        for (int reg = 0; reg < 4; ++reg) {
            const int orow = orow0 + reg;
            if (orow < NN) out[(size_t)orow * 256 + col] = acc[ct][reg] + bias;
        }
    }
}

// ---------------- CSR build ----------------
__global__ void count_deg(const int* __restrict__ dst, int* __restrict__ deg)
{
    int e = blockIdx.x * blockDim.x + threadIdx.x;
    if (e < NE) atomicAdd(&deg[dst[e]], 1);
}

__global__ __launch_bounds__(256) void deg_blocksum(const int* __restrict__ deg,
                                                    int* __restrict__ bsum)
{
    int i = blockIdx.x * 256 + threadIdx.x;
    int v = (i < NN) ? deg[i] : 0;
#pragma unroll
    for (int off = 32; off; off >>= 1) v += __shfl_xor(v, off);
    __shared__ int ws[4];
    if ((threadIdx.x & 63) == 0) ws[threadIdx.x >> 6] = v;
    __syncthreads();
    if (threadIdx.x == 0) bsum[blockIdx.x] = ws[0] + ws[1] + ws[2] + ws[3];
}

__global__ __launch_bounds__(256) void scan_bsum(int* __restrict__ bsum)
{
    __shared__ int tmp[256];
    int t = threadIdx.x;
    int orig = (t < NB) ? bsum[t] : 0;
    tmp[t] = orig;
    __syncthreads();
    for (int off = 1; off < 256; off <<= 1) {
        int v = (t >= off) ? tmp[t - off] : 0;
        __syncthreads();
        tmp[t] += v;
        __syncthreads();
    }
    if (t < NB) bsum[t] = tmp[t] - orig;  // exclusive prefix
}

__global__ __launch_bounds__(256) void write_rows(const int* __restrict__ deg,
                                                  const int* __restrict__ bpre,
                                                  int* __restrict__ row_start,
                                                  int* __restrict__ cursor)
{
    int i = blockIdx.x * 256 + threadIdx.x;
    int d = (i < NN) ? deg[i] : 0;
    int lane = threadIdx.x & 63, w = threadIdx.x >> 6;
    int x = d;
#pragma unroll
    for (int off = 1; off < 64; off <<= 1) {
        int v = __shfl_up(x, off);
        if (lane >= off) x += v;
    }
    __shared__ int wsum[4];
    if (lane == 63) wsum[w] = x;
    __syncthreads();
    int woff = 0;
#pragma unroll
    for (int k = 0; k < 4; ++k)
        if (k < w) woff += wsum[k];
    if (i < NN) {
        int rs = bpre[blockIdx.x] + woff + x - d;
        row_start[i] = rs;
        cursor[i] = rs;
    }
    if (blockIdx.x == 0 && threadIdx.x == 0) row_start[NN] = NE;
}

// cursor pre-initialized to row_start values -> absolute positions
__global__ void scatter_src(const int* __restrict__ src, const int* __restrict__ dst,
                            int* __restrict__ cursor, int* __restrict__ src_sorted)
{
    int e = blockIdx.x * blockDim.x + threadIdx.x;
    if (e < NE) {
        int pos = atomicAdd(&cursor[dst[e]], 1);
        src_sorted[pos] = src[e];
    }
}

// ---- Layer-1 fused, single pass, defer-max, 2-edge software pipeline.
//      block=node, wave=edges (stride 4), lane=4 contiguous dims (coalesced 1KB row).
__global__ __launch_bounds__(256) void gat1_fused(
    const float* __restrict__ hs, const float* __restrict__ hd,
    const float* __restrict__ attn, const int* __restrict__ src_sorted,
    const int* __restrict__ row_start,
    const float* __restrict__ W2s, const float* __restrict__ b2s,
    const float* __restrict__ W2d, const float* __restrict__ b2d,
    float* __restrict__ hs2, float* __restrict__ hd2)
{
    __shared__ float mw[4][4];       // [wave][head] deferred max
    __shared__ float denw[4][4];     // [wave][head] denominator
    __shared__ float4 accs[4][64];   // [wave][lane] accumulators

    const int n = blockIdx.x;
    const int tid = threadIdx.x;
    const int w = tid >> 6;
    const int lane = tid & 63;
    const int q = lane & 15;
    const int hh = lane >> 4;        // head owning this lane's 4 dims
    const int beg = row_start[n], end_ = row_start[n + 1];

    const float4 a4 = *reinterpret_cast<const float4*>(&attn[lane * 4]);
    const float4 y4 = *reinterpret_cast<const float4*>(&hd[(size_t)n * 256 + lane * 4]);

    float m = -INFINITY, den = 0.0f;
    float4 acc = make_float4(0.f, 0.f, 0.f, 0.f);

    int i = beg + w;
    // -------- pipelined pairs: edges (i, i+4) with independent gathers --------
    for (; i + 4 < end_; i += 8) {
        const int sa = __builtin_amdgcn_readfirstlane(src_sorted[i]);
        const int sb = __builtin_amdgcn_readfirstlane(src_sorted[i + 4]);
        const float4 xa = *reinterpret_cast<const float4*>(&hs[(size_t)sa * 256 + lane * 4]);
        const float4 xb = *reinterpret_cast<const float4*>(&hs[(size_t)sb * 256 + lane * 4]);
        float ta, tb, pa, pb;
        ta = xa.x + y4.x; ta = fmaxf(ta, NEG * ta); pa = ta * a4.x;
        tb = xb.x + y4.x; tb = fmaxf(tb, NEG * tb); pb = tb * a4.x;
        ta = xa.y + y4.y; ta = fmaxf(ta, NEG * ta); pa = fmaf(ta, a4.y, pa);
        tb = xb.y + y4.y; tb = fmaxf(tb, NEG * tb); pb = fmaf(tb, a4.y, pb);
        ta = xa.z + y4.z; ta = fmaxf(ta, NEG * ta); pa = fmaf(ta, a4.z, pa);
        tb = xb.z + y4.z; tb = fmaxf(tb, NEG * tb); pb = fmaf(tb, a4.z, pb);
        ta = xa.w + y4.w; ta = fmaxf(ta, NEG * ta); pa = fmaf(ta, a4.w, pa);
        tb = xb.w + y4.w; tb = fmaxf(tb, NEG * tb); pb = fmaf(tb, a4.w, pb);
        pa += __shfl_xor(pa, 1);  pb += __shfl_xor(pb, 1);
        pa += __shfl_xor(pa, 2);  pb += __shfl_xor(pb, 2);
        pa += __shfl_xor(pa, 4);  pb += __shfl_xor(pb, 4);
        pa += __shfl_xor(pa, 8);  pb += __shfl_xor(pb, 8);
        // sequential state update (a then b); rescale is rare (defer-max T13)
        if (pa > m + 8.0f) {
            const float rs = __expf(m - pa);  // first edge: exp(-inf)=0
            den *= rs;
            acc.x *= rs; acc.y *= rs; acc.z *= rs; acc.w *= rs;
            m = pa;
        }
        const float wa = __expf(pa - m);
        den += wa;
        acc.x = fmaf(wa, xa.x, acc.x);
        acc.y = fmaf(wa, xa.y, acc.y);
        acc.z = fmaf(wa, xa.z, acc.z);
        acc.w = fmaf(wa, xa.w, acc.w);
        if (pb > m + 8.0f) {
            const float rs = __expf(m - pb);
            den *= rs;
            acc.x *= rs; acc.y *= rs; acc.z *= rs; acc.w *= rs;
            m = pb;
        }
        const float wb = __expf(pb - m);
        den += wb;
        acc.x = fmaf(wb, xb.x, acc.x);
        acc.y = fmaf(wb, xb.y, acc.y);
        acc.z = fmaf(wb, xb.z, acc.z);
        acc.w = fmaf(wb, xb.w, acc.w);
    }
    // -------- tail (at most one edge for this wave) --------
    if (i < end_) {
        const int s = __builtin_amdgcn_readfirstlane(src_sorted[i]);
        const float4 x = *reinterpret_cast<const float4*>(&hs[(size_t)s * 256 + lane * 4]);
        float t, p;
        t = x.x + y4.x; t = fmaxf(t, NEG * t); p  = t * a4.x;
        t = x.y + y4.y; t = fmaxf(t, NEG * t); p = fmaf(t, a4.y, p);
        t = x.z + y4.z; t = fmaxf(t, NEG * t); p = fmaf(t, a4.z, p);
        t = x.w + y4.w; t = fmaxf(t, NEG * t); p = fmaf(t, a4.w, p);
        p += __shfl_xor(p, 1);
        p += __shfl_xor(p, 2);
        p += __shfl_xor(p, 4);
        p += __shfl_xor(p, 8);
        if (p > m + 8.0f) {
            const float rs = __expf(m - p);
            den *= rs;
            acc.x *= rs; acc.y *= rs; acc.z *= rs; acc.w *= rs;
            m = p;
        }
        const float wv = __expf(p - m);
        den += wv;
        acc.x = fmaf(wv, x.x, acc.x);
        acc.y = fmaf(wv, x.y, acc.y);
        acc.z = fmaf(wv, x.z, acc.z);
        acc.w = fmaf(wv, x.w, acc.w);
    }

    if (q == 0) { mw[w][hh] = m; denw[w][hh] = den; }
    accs[w][lane] = acc;
    __syncthreads();

    if (w == 0) {
        // per-head global max across waves
        const float m0 = mw[0][hh], m1 = mw[1][hh], m2v = mw[2][hh], m3 = mw[3][hh];
        const float M = fmaxf(fmaxf(m0, m1), fmaxf(m2v, m3));
        float4 o = make_float4(0.f, 0.f, 0.f, 0.f);
        float dtot = 0.0f;
#pragma unroll
        for (int k = 0; k < 4; ++k) {
            const float mk = mw[k][hh];
            const float sc = (mk == -INFINITY) ? 0.0f : __expf(mk - M);
            dtot = fmaf(denw[k][hh], sc, dtot);
            const float4 av = accs[k][lane];
            o.x = fmaf(av.x, sc, o.x);
            o.y = fmaf(av.y, sc, o.y);
            o.z = fmaf(av.z, sc, o.z);
            o.w = fmaf(av.w, sc, o.w);
        }
        const float inv = (dtot > 0.0f) ? 1.0f / dtot : 0.0f;
        o.x *= inv; o.y *= inv; o.z *= inv; o.w *= inv;
        // ELU
        o.x = (o.x > 0.0f) ? o.x : __expf(o.x) - 1.0f;
        o.y = (o.y > 0.0f) ? o.y : __expf(o.y) - 1.0f;
        o.z = (o.z > 0.0f) ? o.z : __expf(o.z) - 1.0f;
        o.w = (o.w > 0.0f) ? o.w : __expf(o.w) - 1.0f;
        // fused layer-2 projection: rows 4*lane..4*lane+3 of W2 [256][2]
        const float4 wsa = *reinterpret_cast<const float4*>(&W2s[lane * 8]);
        const float4 wsb = *reinterpret_cast<const float4*>(&W2s[lane * 8 + 4]);
        const float4 wda = *reinterpret_cast<const float4*>(&W2d[lane * 8]);
        const float4 wdb = *reinterpret_cast<const float4*>(&W2d[lane * 8 + 4]);
        float ps0 = o.x * wsa.x + o.y * wsa.z + o.z * wsb.x + o.w * wsb.z;
        float ps1 = o.x * wsa.y + o.y * wsa.w + o.z * wsb.y + o.w * wsb.w;
        float pd0 = o.x * wda.x + o.y * wda.z + o.z * wdb.x + o.w * wdb.z;
        float pd1 = o.x * wda.y + o.y * wda.w + o.z * wdb.y + o.w * wdb.w;
#pragma unroll
        for (int off = 32; off; off >>= 1) {
            ps0 += __shfl_xor(ps0, off);
            ps1 += __shfl_xor(ps1, off);
            pd0 += __shfl_xor(pd0, off);
            pd1 += __shfl_xor(pd1, off);
        }
        if (lane == 0) {
            hs2[(size_t)n * 2 + 0] = ps0 + b2s[0];
            hs2[(size_t)n * 2 + 1] = ps1 + b2s[1];
            hd2[(size_t)n * 2 + 0] = pd0 + b2d[0];
            hd2[(size_t)n * 2 + 1] = pd1 + b2d[1];
        }
    }
}

// ---------------- Layer-2: 16 lanes per node (deg ~16), 16 nodes per block ----
__global__ __launch_bounds__(256) void node2_kernel(
    const float* __restrict__ hs2, const float* __restrict__ hd2,
    const float* __restrict__ attn2, const int* __restrict__ src_sorted,
    const int* __restrict__ row_start, float* __restrict__ out)
{
    const int n = blockIdx.x * 16 + (threadIdx.x >> 4);
    const int q = threadIdx.x & 15;
    if (n >= NN) return;
    const float a0 = attn2[0], a1 = attn2[1];
    const float h0 = hd2[n * 2 + 0], h1v = hd2[n * 2 + 1];
    const int beg = row_start[n], end_ = row_start[n + 1];
    float m = -INFINITY, den = 0.0f, A0 = 0.0f, A1 = 0.0f;
    for (int i = beg + q; i < end_; i += 16) {
        const int s = src_sorted[i];
        float x0 = hs2[s * 2 + 0], x1 = hs2[s * 2 + 1];
        float t0 = x0 + h0;  t0 = fmaxf(t0, NEG * t0);
        float t1 = x1 + h1v; t1 = fmaxf(t1, NEG * t1);
        float p = fmaf(t0, a0, t1 * a1);
        float mn = fmaxf(m, p);
        float c = __expf(m - mn);
        float w = __expf(p - mn);
        den = den * c + w;
        A0 = A0 * c + w * x0;
        A1 = A1 * c + w * x1;
        m = mn;
    }
#pragma unroll
    for (int off = 1; off < 16; off <<= 1) {
        float m2 = __shfl_xor(m, off, 16);
        float d2 = __shfl_xor(den, off, 16);
        float b0 = __shfl_xor(A0, off, 16);
        float b1 = __shfl_xor(A1, off, 16);
        float mn = fmaxf(m, m2);
        float c1 = (m < mn) ? __expf(m - mn) : 1.0f;
        float c2 = (m2 < mn) ? __expf(m2 - mn) : 1.0f;
        den = den * c1 + d2 * c2;
        A0 = A0 * c1 + b0 * c2;
        A1 = A1 * c1 + b1 * c2;
        m = mn;
    }
    if (q == 0) {
        out[n * 2 + 0] = (den > 0.0f) ? A0 / den : 0.0f;
        out[n * 2 + 1] = (den > 0.0f) ? A1 / den : 0.0f;
    }
}

// ---------------- launch ----------------
extern "C" void kernel_launch(void* const* d_in, const int* in_sizes, int n_in,
                              void* d_out, int out_size, void* d_ws, size_t ws_size,
                              hipStream_t stream)
{
    const float* feat  = (const float*)d_in[0];
    const int*   src   = (const int*)d_in[1];
    const int*   dst   = (const int*)d_in[2];
    const float* W1s   = (const float*)d_in[3];
    const float* b1s   = (const float*)d_in[4];
    const float* W1d   = (const float*)d_in[5];
    const float* b1d   = (const float*)d_in[6];
    const float* attn1 = (const float*)d_in[7];
    const float* W2s   = (const float*)d_in[8];
    const float* b2s   = (const float*)d_in[9];
    const float* W2d   = (const float*)d_in[10];
    const float* b2d   = (const float*)d_in[11];
    const float* attn2 = (const float*)d_in[12];
    float* out = (float*)d_out;

    char* ws = (char*)d_ws;
    size_t off = 0;
    auto alloc = [&](size_t bytes) {
        char* p = ws + off;
        off += (bytes + 255) & ~size_t(255);
        return p;
    };
    float*          hs1        = (float*)alloc((size_t)NN * 256 * 4);
    float*          hd1        = (float*)alloc((size_t)NN * 256 * 4);
    unsigned short* fb_hi      = (unsigned short*)alloc((size_t)NN * 128 * 2);
    unsigned short* fb_lo      = (unsigned short*)alloc((size_t)NN * 128 * 2);
    unsigned short* wbs_hi     = (unsigned short*)alloc((size_t)128 * 256 * 2);
    unsigned short* wbs_lo     = (unsigned short*)alloc((size_t)128 * 256 * 2);
    unsigned short* wbd_hi     = (unsigned short*)alloc((size_t)128 * 256 * 2);
    unsigned short* wbd_lo     = (unsigned short*)alloc((size_t)128 * 256 * 2);
    int*            src_sorted = (int*)alloc((size_t)NE * 4);
    int*            row_start  = (int*)alloc((size_t)(NN + 1) * 4);
    int*            deg        = (int*)alloc((size_t)NN * 4);
    int*            cursor     = (int*)alloc((size_t)NN * 4);
    int*            bsum       = (int*)alloc((size_t)NB * 4);
    float*          hs2        = (float*)alloc((size_t)NN * 2 * 4);
    float*          hd2        = (float*)alloc((size_t)NN * 2 * 4);
    (void)ws_size; (void)n_in; (void)in_sizes; (void)out_size;

    hipMemsetAsync(deg, 0, (size_t)NN * 4, stream);

    // ---- projections on matrix cores (split-bf16) ----
    cvt_feat<<<(NN * 128 / 4 + 255) / 256, 256, 0, stream>>>(feat, fb_hi, fb_lo);
    dim3 wgrid(128, 2);
    cvt_w<<<wgrid, 256, 0, stream>>>(W1s, W1d, wbs_hi, wbs_lo, wbd_hi, wbd_lo);
    dim3 ggrid((NN + 63) / 64, 2);
    gemm_mfma<<<ggrid, 256, 0, stream>>>(fb_hi, fb_lo,
                                         wbs_hi, wbs_lo, b1s, hs1,
                                         wbd_hi, wbd_lo, b1d, hd1);

    // ---- CSR build ----
    const int eb = (NE + 255) / 256;
    count_deg<<<eb, 256, 0, stream>>>(dst, deg);
    deg_blocksum<<<NB, 256, 0, stream>>>(deg, bsum);
    scan_bsum<<<1, 256, 0, stream>>>(bsum);
    write_rows<<<NB, 256, 0, stream>>>(deg, bsum, row_start, cursor);
    scatter_src<<<eb, 256, 0, stream>>>(src, dst, cursor, src_sorted);

    gat1_fused<<<NN, 256, 0, stream>>>(hs1, hd1, attn1, src_sorted, row_start,
                                       W2s, b2s, W2d, b2d, hs2, hd2);

    node2_kernel<<<(NN + 15) / 16, 256, 0, stream>>>(hs2, hd2, attn2, src_sorted,
                                                     row_start, out);
}

// Round 12
// 287.533 us; speedup vs baseline: 1.2697x; 1.0107x over previous
//
#include <hip/hip_runtime.h>
#include <math.h>

#define NN 50000
#define NE 800000
#define NEG 0.2f
#define NB 196  // ceil(NN/256)

typedef __attribute__((ext_vector_type(8))) short bf16x8;
typedef __attribute__((ext_vector_type(4))) float f32x4;

__device__ __forceinline__ unsigned short bf16_rne(float x)
{
    unsigned u = __float_as_uint(x);
    return (unsigned short)((u + 0x7FFF + ((u >> 16) & 1)) >> 16);
}
__device__ __forceinline__ float bf16_to_f(unsigned short h)
{
    return __uint_as_float(((unsigned)h) << 16);
}

// ---- split feat f32 -> hi/lo bf16 (row-major [N][128]) ----
__global__ __launch_bounds__(256) void cvt_feat(
    const float* __restrict__ f, unsigned short* __restrict__ hi,
    unsigned short* __restrict__ lo)
{
    const int i = blockIdx.x * 256 + threadIdx.x;   // one float4 per thread
    if (i >= NN * 128 / 4) return;
    const float4 v = reinterpret_cast<const float4*>(f)[i];
    ushort4 h, l;
    h.x = bf16_rne(v.x); l.x = bf16_rne(v.x - bf16_to_f(h.x));
    h.y = bf16_rne(v.y); l.y = bf16_rne(v.y - bf16_to_f(h.y));
    h.z = bf16_rne(v.z); l.z = bf16_rne(v.z - bf16_to_f(h.z));
    h.w = bf16_rne(v.w); l.w = bf16_rne(v.w - bf16_to_f(h.w));
    reinterpret_cast<ushort4*>(hi)[i] = h;
    reinterpret_cast<ushort4*>(lo)[i] = l;
}

// ---- repack W [128][256] f32 -> MFMA fragment order [ks][ct][lane][8], hi/lo bf16 ----
__global__ __launch_bounds__(256) void cvt_w(
    const float* __restrict__ Ws, const float* __restrict__ Wd,
    unsigned short* __restrict__ ShiP, unsigned short* __restrict__ SloP,
    unsigned short* __restrict__ DhiP, unsigned short* __restrict__ DloP)
{
    const int idx = blockIdx.x * 256 + threadIdx.x;   // 0..32767
    const float* W = blockIdx.y ? Wd : Ws;
    unsigned short* oh = blockIdx.y ? DhiP : ShiP;
    unsigned short* ol = blockIdx.y ? DloP : SloP;
    const int j  = idx & 7;
    const int l  = (idx >> 3) & 63;
    const int ct = (idx >> 9) & 15;
    const int ks = idx >> 13;
    const int k   = ks * 32 + ((l >> 4) << 3) + j;
    const int col = (ct << 4) + (l & 15);
    const float x = W[(size_t)k * 256 + col];
    const unsigned short h = bf16_rne(x);
    oh[idx] = h;
    ol[idx] = bf16_rne(x - bf16_to_f(h));
}

// ---- dual GEMM on matrix cores: out[N,256] = feat[N,128] @ W + b (split-bf16, 3 terms)
__global__ __launch_bounds__(256) void gemm_mfma(
    const unsigned short* __restrict__ fhi, const unsigned short* __restrict__ flo,
    const unsigned short* __restrict__ WhS, const unsigned short* __restrict__ WlS,
    const float* __restrict__ bS, float* __restrict__ outS,
    const unsigned short* __restrict__ WhD, const unsigned short* __restrict__ WlD,
    const float* __restrict__ bD, float* __restrict__ outD)
{
    const unsigned short* Wh = blockIdx.y ? WhD : WhS;
    const unsigned short* Wl = blockIdx.y ? WlD : WlS;
    const float* bv = blockIdx.y ? bD : bS;
    float* out      = blockIdx.y ? outD : outS;

    const int tid = threadIdx.x;
    const int w   = tid >> 6;        // wave -> rows w*16..+15
    const int l   = tid & 63;
    const int r16 = l & 15;          // A row within tile
    const int kg  = l >> 4;          // k-group (8 wide)
    const int row0 = blockIdx.x * 64;

    int arow = row0 + w * 16 + r16;
    if (arow >= NN) arow = NN - 1;   // clamp (stores guarded)

    f32x4 acc[16];
#pragma unroll
    for (int ct = 0; ct < 16; ++ct) acc[ct] = (f32x4){0.f, 0.f, 0.f, 0.f};

#pragma unroll
    for (int ks = 0; ks < 4; ++ks) {
        const bf16x8 ah = *reinterpret_cast<const bf16x8*>(
            &fhi[(size_t)arow * 128 + ks * 32 + kg * 8]);
        const bf16x8 al = *reinterpret_cast<const bf16x8*>(
            &flo[(size_t)arow * 128 + ks * 32 + kg * 8]);
#pragma unroll
        for (int ct = 0; ct < 16; ++ct) {
            const size_t boff = ((size_t)(ks * 16 + ct) * 64 + l) * 8;
            const bf16x8 bh = *reinterpret_cast<const bf16x8*>(&Wh[boff]);
            const bf16x8 bl = *reinterpret_cast<const bf16x8*>(&Wl[boff]);
            acc[ct] = __builtin_amdgcn_mfma_f32_16x16x32_bf16(ah, bh, acc[ct], 0, 0, 0);
            acc[ct] = __builtin_amdgcn_mfma_f32_16x16x32_bf16(ah, bl, acc[ct], 0, 0, 0);
            acc[ct] = __builtin_amdgcn_mfma_f32_16x16x32_bf16(al, bh, acc[ct], 0, 0, 0);
        }
    }

    // D layout: col = ct*16 + (lane&15), row = w*16 + (lane>>4)*4 + reg
    const int orow0 = row0 + w * 16 + kg * 4;
#pragma unroll
    for (int ct = 0; ct < 16; ++ct) {
        const int col = ct * 16 + r16;
        const float bias = bv[col];
#pragma unroll
        for (int reg = 0; reg < 4; ++reg) {
            const int orow = orow0 + reg;
            if (orow < NN) out[(size_t)orow * 256 + col] = acc[ct][reg] + bias;
        }
    }
}

// ---------------- CSR build ----------------
__global__ void count_deg(const int* __restrict__ dst, int* __restrict__ deg)
{
    int e = blockIdx.x * blockDim.x + threadIdx.x;
    if (e < NE) atomicAdd(&deg[dst[e]], 1);
}

__global__ __launch_bounds__(256) void deg_blocksum(const int* __restrict__ deg,
                                                    int* __restrict__ bsum)
{
    int i = blockIdx.x * 256 + threadIdx.x;
    int v = (i < NN) ? deg[i] : 0;
#pragma unroll
    for (int off = 32; off; off >>= 1) v += __shfl_xor(v, off);
    __shared__ int ws[4];
    if ((threadIdx.x & 63) == 0) ws[threadIdx.x >> 6] = v;
    __syncthreads();
    if (threadIdx.x == 0) bsum[blockIdx.x] = ws[0] + ws[1] + ws[2] + ws[3];
}

__global__ __launch_bounds__(256) void scan_bsum(int* __restrict__ bsum)
{
    __shared__ int tmp[256];
    int t = threadIdx.x;
    int orig = (t < NB) ? bsum[t] : 0;
    tmp[t] = orig;
    __syncthreads();
    for (int off = 1; off < 256; off <<= 1) {
        int v = (t >= off) ? tmp[t - off] : 0;
        __syncthreads();
        tmp[t] += v;
        __syncthreads();
    }
    if (t < NB) bsum[t] = tmp[t] - orig;  // exclusive prefix
}

__global__ __launch_bounds__(256) void write_rows(const int* __restrict__ deg,
                                                  const int* __restrict__ bpre,
                                                  int* __restrict__ row_start,
                                                  int* __restrict__ cursor)
{
    int i = blockIdx.x * 256 + threadIdx.x;
    int d = (i < NN) ? deg[i] : 0;
    int lane = threadIdx.x & 63, w = threadIdx.x >> 6;
    int x = d;
#pragma unroll
    for (int off = 1; off < 64; off <<= 1) {
        int v = __shfl_up(x, off);
        if (lane >= off) x += v;
    }
    __shared__ int wsum[4];
    if (lane == 63) wsum[w] = x;
    __syncthreads();
    int woff = 0;
#pragma unroll
    for (int k = 0; k < 4; ++k)
        if (k < w) woff += wsum[k];
    if (i < NN) {
        int rs = bpre[blockIdx.x] + woff + x - d;
        row_start[i] = rs;
        cursor[i] = rs;
    }
    if (blockIdx.x == 0 && threadIdx.x == 0) row_start[NN] = NE;
}

// cursor pre-initialized to row_start values -> absolute positions
__global__ void scatter_src(const int* __restrict__ src, const int* __restrict__ dst,
                            int* __restrict__ cursor, int* __restrict__ src_sorted)
{
    int e = blockIdx.x * blockDim.x + threadIdx.x;
    if (e < NE) {
        int pos = atomicAdd(&cursor[dst[e]], 1);
        src_sorted[pos] = src[e];
    }
}

// ---- Layer-1 fused: WAVE = NODE (4 nodes/block). Single pass, defer-max,
//      2-edge pipeline; lane = 4 contiguous dims; no LDS, no barriers.
__global__ __launch_bounds__(256) void gat1_fused(
    const float* __restrict__ hs, const float* __restrict__ hd,
    const float* __restrict__ attn, const int* __restrict__ src_sorted,
    const int* __restrict__ row_start,
    const float* __restrict__ W2s, const float* __restrict__ b2s,
    const float* __restrict__ W2d, const float* __restrict__ b2d,
    float* __restrict__ hs2, float* __restrict__ hd2)
{
    const int n = blockIdx.x * 4 + (threadIdx.x >> 6);   // NN % 4 == 0
    const int lane = threadIdx.x & 63;
    const int beg = row_start[n], end_ = row_start[n + 1];

    const float4 a4 = *reinterpret_cast<const float4*>(&attn[lane * 4]);
    const float4 y4 = *reinterpret_cast<const float4*>(&hd[(size_t)n * 256 + lane * 4]);

    float m = -INFINITY, den = 0.0f;
    float4 acc = make_float4(0.f, 0.f, 0.f, 0.f);

    int i = beg;
    // -------- pipelined pairs: edges (i, i+1) with independent gathers --------
    for (; i + 1 < end_; i += 2) {
        const int sa = __builtin_amdgcn_readfirstlane(src_sorted[i]);
        const int sb = __builtin_amdgcn_readfirstlane(src_sorted[i + 1]);
        const float4 xa = *reinterpret_cast<const float4*>(&hs[(size_t)sa * 256 + lane * 4]);
        const float4 xb = *reinterpret_cast<const float4*>(&hs[(size_t)sb * 256 + lane * 4]);
        float ta, tb, pa, pb;
        ta = xa.x + y4.x; ta = fmaxf(ta, NEG * ta); pa = ta * a4.x;
        tb = xb.x + y4.x; tb = fmaxf(tb, NEG * tb); pb = tb * a4.x;
        ta = xa.y + y4.y; ta = fmaxf(ta, NEG * ta); pa = fmaf(ta, a4.y, pa);
        tb = xb.y + y4.y; tb = fmaxf(tb, NEG * tb); pb = fmaf(tb, a4.y, pb);
        ta = xa.z + y4.z; ta = fmaxf(ta, NEG * ta); pa = fmaf(ta, a4.z, pa);
        tb = xb.z + y4.z; tb = fmaxf(tb, NEG * tb); pb = fmaf(tb, a4.z, pb);
        ta = xa.w + y4.w; ta = fmaxf(ta, NEG * ta); pa = fmaf(ta, a4.w, pa);
        tb = xb.w + y4.w; tb = fmaxf(tb, NEG * tb); pb = fmaf(tb, a4.w, pb);
        pa += __shfl_xor(pa, 1);  pb += __shfl_xor(pb, 1);
        pa += __shfl_xor(pa, 2);  pb += __shfl_xor(pb, 2);
        pa += __shfl_xor(pa, 4);  pb += __shfl_xor(pb, 4);
        pa += __shfl_xor(pa, 8);  pb += __shfl_xor(pb, 8);
        // per-16-lane-group (head) score; m/den uniform within group
        if (pa > m + 8.0f) {              // rare deferred rescale (T13)
            const float rs = __expf(m - pa);  // first edge: exp(-inf)=0
            den *= rs;
            acc.x *= rs; acc.y *= rs; acc.z *= rs; acc.w *= rs;
            m = pa;
        }
        const float wa = __expf(pa - m);
        den += wa;
        acc.x = fmaf(wa, xa.x, acc.x);
        acc.y = fmaf(wa, xa.y, acc.y);
        acc.z = fmaf(wa, xa.z, acc.z);
        acc.w = fmaf(wa, xa.w, acc.w);
        if (pb > m + 8.0f) {
            const float rs = __expf(m - pb);
            den *= rs;
            acc.x *= rs; acc.y *= rs; acc.z *= rs; acc.w *= rs;
            m = pb;
        }
        const float wb = __expf(pb - m);
        den += wb;
        acc.x = fmaf(wb, xb.x, acc.x);
        acc.y = fmaf(wb, xb.y, acc.y);
        acc.z = fmaf(wb, xb.z, acc.z);
        acc.w = fmaf(wb, xb.w, acc.w);
    }
    // -------- tail (at most one edge) --------
    if (i < end_) {
        const int s = __builtin_amdgcn_readfirstlane(src_sorted[i]);
        const float4 x = *reinterpret_cast<const float4*>(&hs[(size_t)s * 256 + lane * 4]);
        float t, p;
        t = x.x + y4.x; t = fmaxf(t, NEG * t); p  = t * a4.x;
        t = x.y + y4.y; t = fmaxf(t, NEG * t); p = fmaf(t, a4.y, p);
        t = x.z + y4.z; t = fmaxf(t, NEG * t); p = fmaf(t, a4.z, p);
        t = x.w + y4.w; t = fmaxf(t, NEG * t); p = fmaf(t, a4.w, p);
        p += __shfl_xor(p, 1);
        p += __shfl_xor(p, 2);
        p += __shfl_xor(p, 4);
        p += __shfl_xor(p, 8);
        if (p > m + 8.0f) {
            const float rs = __expf(m - p);
            den *= rs;
            acc.x *= rs; acc.y *= rs; acc.z *= rs; acc.w *= rs;
            m = p;
        }
        const float wv = __expf(p - m);
        den += wv;
        acc.x = fmaf(wv, x.x, acc.x);
        acc.y = fmaf(wv, x.y, acc.y);
        acc.z = fmaf(wv, x.z, acc.z);
        acc.w = fmaf(wv, x.w, acc.w);
    }

    // -------- in-wave epilogue: normalize, ELU, layer-2 projection --------
    const float inv = (den > 0.0f) ? 1.0f / den : 0.0f;   // uniform per 16-lane group
    float4 o;
    o.x = acc.x * inv; o.y = acc.y * inv; o.z = acc.z * inv; o.w = acc.w * inv;
    o.x = (o.x > 0.0f) ? o.x : __expf(o.x) - 1.0f;
    o.y = (o.y > 0.0f) ? o.y : __expf(o.y) - 1.0f;
    o.z = (o.z > 0.0f) ? o.z : __expf(o.z) - 1.0f;
    o.w = (o.w > 0.0f) ? o.w : __expf(o.w) - 1.0f;

    const float4 wsa = *reinterpret_cast<const float4*>(&W2s[lane * 8]);
    const float4 wsb = *reinterpret_cast<const float4*>(&W2s[lane * 8 + 4]);
    const float4 wda = *reinterpret_cast<const float4*>(&W2d[lane * 8]);
    const float4 wdb = *reinterpret_cast<const float4*>(&W2d[lane * 8 + 4]);
    float ps0 = o.x * wsa.x + o.y * wsa.z + o.z * wsb.x + o.w * wsb.z;
    float ps1 = o.x * wsa.y + o.y * wsa.w + o.z * wsb.y + o.w * wsb.w;
    float pd0 = o.x * wda.x + o.y * wda.z + o.z * wdb.x + o.w * wdb.z;
    float pd1 = o.x * wda.y + o.y * wda.w + o.z * wdb.y + o.w * wdb.w;
#pragma unroll
    for (int off = 32; off; off >>= 1) {
        ps0 += __shfl_xor(ps0, off);
        ps1 += __shfl_xor(ps1, off);
        pd0 += __shfl_xor(pd0, off);
        pd1 += __shfl_xor(pd1, off);
    }
    if (lane == 0) {
        hs2[(size_t)n * 2 + 0] = ps0 + b2s[0];
        hs2[(size_t)n * 2 + 1] = ps1 + b2s[1];
        hd2[(size_t)n * 2 + 0] = pd0 + b2d[0];
        hd2[(size_t)n * 2 + 1] = pd1 + b2d[1];
    }
}

// ---------------- Layer-2: 16 lanes per node (deg ~16), 16 nodes per block ----
__global__ __launch_bounds__(256) void node2_kernel(
    const float* __restrict__ hs2, const float* __restrict__ hd2,
    const float* __restrict__ attn2, const int* __restrict__ src_sorted,
    const int* __restrict__ row_start, float* __restrict__ out)
{
    const int n = blockIdx.x * 16 + (threadIdx.x >> 4);
    const int q = threadIdx.x & 15;
    if (n >= NN) return;
    const float a0 = attn2[0], a1 = attn2[1];
    const float h0 = hd2[n * 2 + 0], h1v = hd2[n * 2 + 1];
    const int beg = row_start[n], end_ = row_start[n + 1];
    float m = -INFINITY, den = 0.0f, A0 = 0.0f, A1 = 0.0f;
    for (int i = beg + q; i < end_; i += 16) {
        const int s = src_sorted[i];
        float x0 = hs2[s * 2 + 0], x1 = hs2[s * 2 + 1];
        float t0 = x0 + h0;  t0 = fmaxf(t0, NEG * t0);
        float t1 = x1 + h1v; t1 = fmaxf(t1, NEG * t1);
        float p = fmaf(t0, a0, t1 * a1);
        float mn = fmaxf(m, p);
        float c = __expf(m - mn);
        float w = __expf(p - mn);
        den = den * c + w;
        A0 = A0 * c + w * x0;
        A1 = A1 * c + w * x1;
        m = mn;
    }
#pragma unroll
    for (int off = 1; off < 16; off <<= 1) {
        float m2 = __shfl_xor(m, off, 16);
        float d2 = __shfl_xor(den, off, 16);
        float b0 = __shfl_xor(A0, off, 16);
        float b1 = __shfl_xor(A1, off, 16);
        float mn = fmaxf(m, m2);
        float c1 = (m < mn) ? __expf(m - mn) : 1.0f;
        float c2 = (m2 < mn) ? __expf(m2 - mn) : 1.0f;
        den = den * c1 + d2 * c2;
        A0 = A0 * c1 + b0 * c2;
        A1 = A1 * c1 + b1 * c2;
        m = mn;
    }
    if (q == 0) {
        out[n * 2 + 0] = (den > 0.0f) ? A0 / den : 0.0f;
        out[n * 2 + 1] = (den > 0.0f) ? A1 / den : 0.0f;
    }
}

// ---------------- launch ----------------
extern "C" void kernel_launch(void* const* d_in, const int* in_sizes, int n_in,
                              void* d_out, int out_size, void* d_ws, size_t ws_size,
                              hipStream_t stream)
{
    const float* feat  = (const float*)d_in[0];
    const int*   src   = (const int*)d_in[1];
    const int*   dst   = (const int*)d_in[2];
    const float* W1s   = (const float*)d_in[3];
    const float* b1s   = (const float*)d_in[4];
    const float* W1d   = (const float*)d_in[5];
    const float* b1d   = (const float*)d_in[6];
    const float* attn1 = (const float*)d_in[7];
    const float* W2s   = (const float*)d_in[8];
    const float* b2s   = (const float*)d_in[9];
    const float* W2d   = (const float*)d_in[10];
    const float* b2d   = (const float*)d_in[11];
    const float* attn2 = (const float*)d_in[12];
    float* out = (float*)d_out;

    char* ws = (char*)d_ws;
    size_t off = 0;
    auto alloc = [&](size_t bytes) {
        char* p = ws + off;
        off += (bytes + 255) & ~size_t(255);
        return p;
    };
    float*          hs1        = (float*)alloc((size_t)NN * 256 * 4);
    float*          hd1        = (float*)alloc((size_t)NN * 256 * 4);
    unsigned short* fb_hi      = (unsigned short*)alloc((size_t)NN * 128 * 2);
    unsigned short* fb_lo      = (unsigned short*)alloc((size_t)NN * 128 * 2);
    unsigned short* wbs_hi     = (unsigned short*)alloc((size_t)128 * 256 * 2);
    unsigned short* wbs_lo     = (unsigned short*)alloc((size_t)128 * 256 * 2);
    unsigned short* wbd_hi     = (unsigned short*)alloc((size_t)128 * 256 * 2);
    unsigned short* wbd_lo     = (unsigned short*)alloc((size_t)128 * 256 * 2);
    int*            src_sorted = (int*)alloc((size_t)NE * 4);
    int*            row_start  = (int*)alloc((size_t)(NN + 1) * 4);
    int*            deg        = (int*)alloc((size_t)NN * 4);
    int*            cursor     = (int*)alloc((size_t)NN * 4);
    int*            bsum       = (int*)alloc((size_t)NB * 4);
    float*          hs2        = (float*)alloc((size_t)NN * 2 * 4);
    float*          hd2        = (float*)alloc((size_t)NN * 2 * 4);
    (void)ws_size; (void)n_in; (void)in_sizes; (void)out_size;

    hipMemsetAsync(deg, 0, (size_t)NN * 4, stream);

    // ---- projections on matrix cores (split-bf16) ----
    cvt_feat<<<(NN * 128 / 4 + 255) / 256, 256, 0, stream>>>(feat, fb_hi, fb_lo);
    dim3 wgrid(128, 2);
    cvt_w<<<wgrid, 256, 0, stream>>>(W1s, W1d, wbs_hi, wbs_lo, wbd_hi, wbd_lo);
    dim3 ggrid((NN + 63) / 64, 2);
    gemm_mfma<<<ggrid, 256, 0, stream>>>(fb_hi, fb_lo,
                                         wbs_hi, wbs_lo, b1s, hs1,
                                         wbd_hi, wbd_lo, b1d, hd1);

    // ---- CSR build ----
    const int eb = (NE + 255) / 256;
    count_deg<<<eb, 256, 0, stream>>>(dst, deg);
    deg_blocksum<<<NB, 256, 0, stream>>>(deg, bsum);
    scan_bsum<<<1, 256, 0, stream>>>(bsum);
    write_rows<<<NB, 256, 0, stream>>>(deg, bsum, row_start, cursor);
    scatter_src<<<eb, 256, 0, stream>>>(src, dst, cursor, src_sorted);

    gat1_fused<<<NN / 4, 256, 0, stream>>>(hs1, hd1, attn1, src_sorted, row_start,
                                           W2s, b2s, W2d, b2d, hs2, hd2);

    node2_kernel<<<(NN + 15) / 16, 256, 0, stream>>>(hs2, hd2, attn2, src_sorted,
                                                     row_start, out);
}

// Round 13
// 269.497 us; speedup vs baseline: 1.3547x; 1.0669x over previous
//
#include <hip/hip_runtime.h>
#include <math.h>

#define NN 50000
#define NE 800000
#define NEG 0.2f
#define NB 196  // ceil(NN/256)

typedef __attribute__((ext_vector_type(8))) short bf16x8;
typedef __attribute__((ext_vector_type(4))) float f32x4;
typedef __attribute__((ext_vector_type(4))) _Float16 half4;

__device__ __forceinline__ unsigned short bf16_rne(float x)
{
    unsigned u = __float_as_uint(x);
    return (unsigned short)((u + 0x7FFF + ((u >> 16) & 1)) >> 16);
}
__device__ __forceinline__ float bf16_to_f(unsigned short h)
{
    return __uint_as_float(((unsigned)h) << 16);
}

// ---- split feat f32 -> hi/lo bf16 (row-major [N][128]) ----
__global__ __launch_bounds__(256) void cvt_feat(
    const float* __restrict__ f, unsigned short* __restrict__ hi,
    unsigned short* __restrict__ lo)
{
    const int i = blockIdx.x * 256 + threadIdx.x;   // one float4 per thread
    if (i >= NN * 128 / 4) return;
    const float4 v = reinterpret_cast<const float4*>(f)[i];
    ushort4 h, l;
    h.x = bf16_rne(v.x); l.x = bf16_rne(v.x - bf16_to_f(h.x));
    h.y = bf16_rne(v.y); l.y = bf16_rne(v.y - bf16_to_f(h.y));
    h.z = bf16_rne(v.z); l.z = bf16_rne(v.z - bf16_to_f(h.z));
    h.w = bf16_rne(v.w); l.w = bf16_rne(v.w - bf16_to_f(h.w));
    reinterpret_cast<ushort4*>(hi)[i] = h;
    reinterpret_cast<ushort4*>(lo)[i] = l;
}

// ---- repack W [128][256] f32 -> MFMA fragment order [ks][ct][lane][8], hi/lo bf16 ----
__global__ __launch_bounds__(256) void cvt_w(
    const float* __restrict__ Ws, const float* __restrict__ Wd,
    unsigned short* __restrict__ ShiP, unsigned short* __restrict__ SloP,
    unsigned short* __restrict__ DhiP, unsigned short* __restrict__ DloP)
{
    const int idx = blockIdx.x * 256 + threadIdx.x;   // 0..32767
    const float* W = blockIdx.y ? Wd : Ws;
    unsigned short* oh = blockIdx.y ? DhiP : ShiP;
    unsigned short* ol = blockIdx.y ? DloP : SloP;
    const int j  = idx & 7;
    const int l  = (idx >> 3) & 63;
    const int ct = (idx >> 9) & 15;
    const int ks = idx >> 13;
    const int k   = ks * 32 + ((l >> 4) << 3) + j;
    const int col = (ct << 4) + (l & 15);
    const float x = W[(size_t)k * 256 + col];
    const unsigned short h = bf16_rne(x);
    oh[idx] = h;
    ol[idx] = bf16_rne(x - bf16_to_f(h));
}

// ---- dual GEMM on matrix cores (split-bf16, 3 terms).
//      y==0: source proj -> fp16 output; y==1: dest proj -> f32 output.
__global__ __launch_bounds__(256) void gemm_mfma(
    const unsigned short* __restrict__ fhi, const unsigned short* __restrict__ flo,
    const unsigned short* __restrict__ WhS, const unsigned short* __restrict__ WlS,
    const float* __restrict__ bS, _Float16* __restrict__ outS,
    const unsigned short* __restrict__ WhD, const unsigned short* __restrict__ WlD,
    const float* __restrict__ bD, float* __restrict__ outD)
{
    const unsigned short* Wh = blockIdx.y ? WhD : WhS;
    const unsigned short* Wl = blockIdx.y ? WlD : WlS;
    const float* bv = blockIdx.y ? bD : bS;

    const int tid = threadIdx.x;
    const int w   = tid >> 6;        // wave -> rows w*16..+15
    const int l   = tid & 63;
    const int r16 = l & 15;          // A row within tile
    const int kg  = l >> 4;          // k-group (8 wide)
    const int row0 = blockIdx.x * 64;

    int arow = row0 + w * 16 + r16;
    if (arow >= NN) arow = NN - 1;   // clamp (stores guarded)

    f32x4 acc[16];
#pragma unroll
    for (int ct = 0; ct < 16; ++ct) acc[ct] = (f32x4){0.f, 0.f, 0.f, 0.f};

#pragma unroll
    for (int ks = 0; ks < 4; ++ks) {
        const bf16x8 ah = *reinterpret_cast<const bf16x8*>(
            &fhi[(size_t)arow * 128 + ks * 32 + kg * 8]);
        const bf16x8 al = *reinterpret_cast<const bf16x8*>(
            &flo[(size_t)arow * 128 + ks * 32 + kg * 8]);
#pragma unroll
        for (int ct = 0; ct < 16; ++ct) {
            const size_t boff = ((size_t)(ks * 16 + ct) * 64 + l) * 8;
            const bf16x8 bh = *reinterpret_cast<const bf16x8*>(&Wh[boff]);
            const bf16x8 bl = *reinterpret_cast<const bf16x8*>(&Wl[boff]);
            acc[ct] = __builtin_amdgcn_mfma_f32_16x16x32_bf16(ah, bh, acc[ct], 0, 0, 0);
            acc[ct] = __builtin_amdgcn_mfma_f32_16x16x32_bf16(ah, bl, acc[ct], 0, 0, 0);
            acc[ct] = __builtin_amdgcn_mfma_f32_16x16x32_bf16(al, bh, acc[ct], 0, 0, 0);
        }
    }

    // D layout: col = ct*16 + (lane&15), row = w*16 + (lane>>4)*4 + reg
    const int orow0 = row0 + w * 16 + kg * 4;
    if (blockIdx.y == 0) {
#pragma unroll
        for (int ct = 0; ct < 16; ++ct) {
            const int col = ct * 16 + r16;
            const float bias = bv[col];
#pragma unroll
            for (int reg = 0; reg < 4; ++reg) {
                const int orow = orow0 + reg;
                if (orow < NN)
                    outS[(size_t)orow * 256 + col] = (_Float16)(acc[ct][reg] + bias);
            }
        }
    } else {
#pragma unroll
        for (int ct = 0; ct < 16; ++ct) {
            const int col = ct * 16 + r16;
            const float bias = bv[col];
#pragma unroll
            for (int reg = 0; reg < 4; ++reg) {
                const int orow = orow0 + reg;
                if (orow < NN)
                    outD[(size_t)orow * 256 + col] = acc[ct][reg] + bias;
            }
        }
    }
}

// ---------------- CSR build ----------------
__global__ void count_deg(const int* __restrict__ dst, int* __restrict__ deg)
{
    int e = blockIdx.x * blockDim.x + threadIdx.x;
    if (e < NE) atomicAdd(&deg[dst[e]], 1);
}

__global__ __launch_bounds__(256) void deg_blocksum(const int* __restrict__ deg,
                                                    int* __restrict__ bsum)
{
    int i = blockIdx.x * 256 + threadIdx.x;
    int v = (i < NN) ? deg[i] : 0;
#pragma unroll
    for (int off = 32; off; off >>= 1) v += __shfl_xor(v, off);
    __shared__ int ws[4];
    if ((threadIdx.x & 63) == 0) ws[threadIdx.x >> 6] = v;
    __syncthreads();
    if (threadIdx.x == 0) bsum[blockIdx.x] = ws[0] + ws[1] + ws[2] + ws[3];
}

__global__ __launch_bounds__(256) void scan_bsum(int* __restrict__ bsum)
{
    __shared__ int tmp[256];
    int t = threadIdx.x;
    int orig = (t < NB) ? bsum[t] : 0;
    tmp[t] = orig;
    __syncthreads();
    for (int off = 1; off < 256; off <<= 1) {
        int v = (t >= off) ? tmp[t - off] : 0;
        __syncthreads();
        tmp[t] += v;
        __syncthreads();
    }
    if (t < NB) bsum[t] = tmp[t] - orig;  // exclusive prefix
}

__global__ __launch_bounds__(256) void write_rows(const int* __restrict__ deg,
                                                  const int* __restrict__ bpre,
                                                  int* __restrict__ row_start,
                                                  int* __restrict__ cursor)
{
    int i = blockIdx.x * 256 + threadIdx.x;
    int d = (i < NN) ? deg[i] : 0;
    int lane = threadIdx.x & 63, w = threadIdx.x >> 6;
    int x = d;
#pragma unroll
    for (int off = 1; off < 64; off <<= 1) {
        int v = __shfl_up(x, off);
        if (lane >= off) x += v;
    }
    __shared__ int wsum[4];
    if (lane == 63) wsum[w] = x;
    __syncthreads();
    int woff = 0;
#pragma unroll
    for (int k = 0; k < 4; ++k)
        if (k < w) woff += wsum[k];
    if (i < NN) {
        int rs = bpre[blockIdx.x] + woff + x - d;
        row_start[i] = rs;
        cursor[i] = rs;
    }
    if (blockIdx.x == 0 && threadIdx.x == 0) row_start[NN] = NE;
}

// cursor pre-initialized to row_start values -> absolute positions
__global__ void scatter_src(const int* __restrict__ src, const int* __restrict__ dst,
                            int* __restrict__ cursor, int* __restrict__ src_sorted)
{
    int e = blockIdx.x * blockDim.x + threadIdx.x;
    if (e < NE) {
        int pos = atomicAdd(&cursor[dst[e]], 1);
        src_sorted[pos] = src[e];
    }
}

// ---- Layer-1 fused: WAVE = NODE (4 nodes/block). Single pass, defer-max,
//      4-edge pipeline; lane = 4 contiguous dims; hs gathered in fp16 (512B/edge).
__global__ __launch_bounds__(256) void gat1_fused(
    const _Float16* __restrict__ hs, const float* __restrict__ hd,
    const float* __restrict__ attn, const int* __restrict__ src_sorted,
    const int* __restrict__ row_start,
    const float* __restrict__ W2s, const float* __restrict__ b2s,
    const float* __restrict__ W2d, const float* __restrict__ b2d,
    float* __restrict__ hs2, float* __restrict__ hd2)
{
    const int n = blockIdx.x * 4 + (threadIdx.x >> 6);   // NN % 4 == 0
    const int lane = threadIdx.x & 63;
    const int beg = row_start[n], end_ = row_start[n + 1];

    const float4 a4 = *reinterpret_cast<const float4*>(&attn[lane * 4]);
    const float4 y4 = *reinterpret_cast<const float4*>(&hd[(size_t)n * 256 + lane * 4]);

    float m = -INFINITY, den = 0.0f;
    float4 acc = make_float4(0.f, 0.f, 0.f, 0.f);

#define SCORE(xf, p)                                                        \
    {                                                                       \
        float t;                                                            \
        t = xf.x + y4.x; t = fmaxf(t, NEG * t); p = t * a4.x;               \
        t = xf.y + y4.y; t = fmaxf(t, NEG * t); p = fmaf(t, a4.y, p);       \
        t = xf.z + y4.z; t = fmaxf(t, NEG * t); p = fmaf(t, a4.z, p);       \
        t = xf.w + y4.w; t = fmaxf(t, NEG * t); p = fmaf(t, a4.w, p);       \
    }
#define UPDATE(xf, p)                                                       \
    {                                                                       \
        if (p > m + 8.0f) {                                                 \
            const float rs = __expf(m - p);                                 \
            den *= rs;                                                      \
            acc.x *= rs; acc.y *= rs; acc.z *= rs; acc.w *= rs;             \
            m = p;                                                          \
        }                                                                   \
        const float wv = __expf(p - m);                                     \
        den += wv;                                                          \
        acc.x = fmaf(wv, xf.x, acc.x);                                      \
        acc.y = fmaf(wv, xf.y, acc.y);                                      \
        acc.z = fmaf(wv, xf.z, acc.z);                                      \
        acc.w = fmaf(wv, xf.w, acc.w);                                      \
    }

    int i = beg;
    // -------- 4-edge pipeline: 4 independent 512B gathers in flight --------
    for (; i + 3 < end_; i += 4) {
        const int s0 = __builtin_amdgcn_readfirstlane(src_sorted[i]);
        const int s1 = __builtin_amdgcn_readfirstlane(src_sorted[i + 1]);
        const int s2 = __builtin_amdgcn_readfirstlane(src_sorted[i + 2]);
        const int s3 = __builtin_amdgcn_readfirstlane(src_sorted[i + 3]);
        const half4 h0 = *reinterpret_cast<const half4*>(&hs[(size_t)s0 * 256 + lane * 4]);
        const half4 h1 = *reinterpret_cast<const half4*>(&hs[(size_t)s1 * 256 + lane * 4]);
        const half4 h2 = *reinterpret_cast<const half4*>(&hs[(size_t)s2 * 256 + lane * 4]);
        const half4 h3 = *reinterpret_cast<const half4*>(&hs[(size_t)s3 * 256 + lane * 4]);
        const float4 x0 = make_float4(h0.x, h0.y, h0.z, h0.w);
        const float4 x1 = make_float4(h1.x, h1.y, h1.z, h1.w);
        const float4 x2 = make_float4(h2.x, h2.y, h2.z, h2.w);
        const float4 x3 = make_float4(h3.x, h3.y, h3.z, h3.w);
        float p0, p1, p2, p3;
        SCORE(x0, p0) SCORE(x1, p1) SCORE(x2, p2) SCORE(x3, p3)
        p0 += __shfl_xor(p0, 1); p1 += __shfl_xor(p1, 1);
        p2 += __shfl_xor(p2, 1); p3 += __shfl_xor(p3, 1);
        p0 += __shfl_xor(p0, 2); p1 += __shfl_xor(p1, 2);
        p2 += __shfl_xor(p2, 2); p3 += __shfl_xor(p3, 2);
        p0 += __shfl_xor(p0, 4); p1 += __shfl_xor(p1, 4);
        p2 += __shfl_xor(p2, 4); p3 += __shfl_xor(p3, 4);
        p0 += __shfl_xor(p0, 8); p1 += __shfl_xor(p1, 8);
        p2 += __shfl_xor(p2, 8); p3 += __shfl_xor(p3, 8);
        UPDATE(x0, p0) UPDATE(x1, p1) UPDATE(x2, p2) UPDATE(x3, p3)
    }
    // -------- tail (up to 3 edges) --------
    for (; i < end_; ++i) {
        const int s = __builtin_amdgcn_readfirstlane(src_sorted[i]);
        const half4 hx = *reinterpret_cast<const half4*>(&hs[(size_t)s * 256 + lane * 4]);
        const float4 x = make_float4(hx.x, hx.y, hx.z, hx.w);
        float p;
        SCORE(x, p)
        p += __shfl_xor(p, 1);
        p += __shfl_xor(p, 2);
        p += __shfl_xor(p, 4);
        p += __shfl_xor(p, 8);
        UPDATE(x, p)
    }
#undef SCORE
#undef UPDATE

    // -------- in-wave epilogue: normalize, ELU, layer-2 projection --------
    const float inv = (den > 0.0f) ? 1.0f / den : 0.0f;   // uniform per 16-lane group
    float4 o;
    o.x = acc.x * inv; o.y = acc.y * inv; o.z = acc.z * inv; o.w = acc.w * inv;
    o.x = (o.x > 0.0f) ? o.x : __expf(o.x) - 1.0f;
    o.y = (o.y > 0.0f) ? o.y : __expf(o.y) - 1.0f;
    o.z = (o.z > 0.0f) ? o.z : __expf(o.z) - 1.0f;
    o.w = (o.w > 0.0f) ? o.w : __expf(o.w) - 1.0f;

    const float4 wsa = *reinterpret_cast<const float4*>(&W2s[lane * 8]);
    const float4 wsb = *reinterpret_cast<const float4*>(&W2s[lane * 8 + 4]);
    const float4 wda = *reinterpret_cast<const float4*>(&W2d[lane * 8]);
    const float4 wdb = *reinterpret_cast<const float4*>(&W2d[lane * 8 + 4]);
    float ps0 = o.x * wsa.x + o.y * wsa.z + o.z * wsb.x + o.w * wsb.z;
    float ps1 = o.x * wsa.y + o.y * wsa.w + o.z * wsb.y + o.w * wsb.w;
    float pd0 = o.x * wda.x + o.y * wda.z + o.z * wdb.x + o.w * wdb.z;
    float pd1 = o.x * wda.y + o.y * wda.w + o.z * wdb.y + o.w * wdb.w;
#pragma unroll
    for (int off = 32; off; off >>= 1) {
        ps0 += __shfl_xor(ps0, off);
        ps1 += __shfl_xor(ps1, off);
        pd0 += __shfl_xor(pd0, off);
        pd1 += __shfl_xor(pd1, off);
    }
    if (lane == 0) {
        hs2[(size_t)n * 2 + 0] = ps0 + b2s[0];
        hs2[(size_t)n * 2 + 1] = ps1 + b2s[1];
        hd2[(size_t)n * 2 + 0] = pd0 + b2d[0];
        hd2[(size_t)n * 2 + 1] = pd1 + b2d[1];
    }
}

// ---------------- Layer-2: 16 lanes per node (deg ~16), 16 nodes per block ----
__global__ __launch_bounds__(256) void node2_kernel(
    const float* __restrict__ hs2, const float* __restrict__ hd2,
    const float* __restrict__ attn2, const int* __restrict__ src_sorted,
    const int* __restrict__ row_start, float* __restrict__ out)
{
    const int n = blockIdx.x * 16 + (threadIdx.x >> 4);
    const int q = threadIdx.x & 15;
    if (n >= NN) return;
    const float a0 = attn2[0], a1 = attn2[1];
    const float h0 = hd2[n * 2 + 0], h1v = hd2[n * 2 + 1];
    const int beg = row_start[n], end_ = row_start[n + 1];
    float m = -INFINITY, den = 0.0f, A0 = 0.0f, A1 = 0.0f;
    for (int i = beg + q; i < end_; i += 16) {
        const int s = src_sorted[i];
        float x0 = hs2[s * 2 + 0], x1 = hs2[s * 2 + 1];
        float t0 = x0 + h0;  t0 = fmaxf(t0, NEG * t0);
        float t1 = x1 + h1v; t1 = fmaxf(t1, NEG * t1);
        float p = fmaf(t0, a0, t1 * a1);
        float mn = fmaxf(m, p);
        float c = __expf(m - mn);
        float w = __expf(p - mn);
        den = den * c + w;
        A0 = A0 * c + w * x0;
        A1 = A1 * c + w * x1;
        m = mn;
    }
#pragma unroll
    for (int off = 1; off < 16; off <<= 1) {
        float m2 = __shfl_xor(m, off, 16);
        float d2 = __shfl_xor(den, off, 16);
        float b0 = __shfl_xor(A0, off, 16);
        float b1 = __shfl_xor(A1, off, 16);
        float mn = fmaxf(m, m2);
        float c1 = (m < mn) ? __expf(m - mn) : 1.0f;
        float c2 = (m2 < mn) ? __expf(m2 - mn) : 1.0f;
        den = den * c1 + d2 * c2;
        A0 = A0 * c1 + b0 * c2;
        A1 = A1 * c1 + b1 * c2;
        m = mn;
    }
    if (q == 0) {
        out[n * 2 + 0] = (den > 0.0f) ? A0 / den : 0.0f;
        out[n * 2 + 1] = (den > 0.0f) ? A1 / den : 0.0f;
    }
}

// ---------------- launch ----------------
extern "C" void kernel_launch(void* const* d_in, const int* in_sizes, int n_in,
                              void* d_out, int out_size, void* d_ws, size_t ws_size,
                              hipStream_t stream)
{
    const float* feat  = (const float*)d_in[0];
    const int*   src   = (const int*)d_in[1];
    const int*   dst   = (const int*)d_in[2];
    const float* W1s   = (const float*)d_in[3];
    const float* b1s   = (const float*)d_in[4];
    const float* W1d   = (const float*)d_in[5];
    const float* b1d   = (const float*)d_in[6];
    const float* attn1 = (const float*)d_in[7];
    const float* W2s   = (const float*)d_in[8];
    const float* b2s   = (const float*)d_in[9];
    const float* W2d   = (const float*)d_in[10];
    const float* b2d   = (const float*)d_in[11];
    const float* attn2 = (const float*)d_in[12];
    float* out = (float*)d_out;

    char* ws = (char*)d_ws;
    size_t off = 0;
    auto alloc = [&](size_t bytes) {
        char* p = ws + off;
        off += (bytes + 255) & ~size_t(255);
        return p;
    };
    _Float16*       hs1h       = (_Float16*)alloc((size_t)NN * 256 * 2);
    float*          hd1        = (float*)alloc((size_t)NN * 256 * 4);
    unsigned short* fb_hi      = (unsigned short*)alloc((size_t)NN * 128 * 2);
    unsigned short* fb_lo      = (unsigned short*)alloc((size_t)NN * 128 * 2);
    unsigned short* wbs_hi     = (unsigned short*)alloc((size_t)128 * 256 * 2);
    unsigned short* wbs_lo     = (unsigned short*)alloc((size_t)128 * 256 * 2);
    unsigned short* wbd_hi     = (unsigned short*)alloc((size_t)128 * 256 * 2);
    unsigned short* wbd_lo     = (unsigned short*)alloc((size_t)128 * 256 * 2);
    int*            src_sorted = (int*)alloc((size_t)NE * 4);
    int*            row_start  = (int*)alloc((size_t)(NN + 1) * 4);
    int*            deg        = (int*)alloc((size_t)NN * 4);
    int*            cursor     = (int*)alloc((size_t)NN * 4);
    int*            bsum       = (int*)alloc((size_t)NB * 4);
    float*          hs2        = (float*)alloc((size_t)NN * 2 * 4);
    float*          hd2        = (float*)alloc((size_t)NN * 2 * 4);
    (void)ws_size; (void)n_in; (void)in_sizes; (void)out_size;

    hipMemsetAsync(deg, 0, (size_t)NN * 4, stream);

    // ---- projections on matrix cores (split-bf16) ----
    cvt_feat<<<(NN * 128 / 4 + 255) / 256, 256, 0, stream>>>(feat, fb_hi, fb_lo);
    dim3 wgrid(128, 2);
    cvt_w<<<wgrid, 256, 0, stream>>>(W1s, W1d, wbs_hi, wbs_lo, wbd_hi, wbd_lo);
    dim3 ggrid((NN + 63) / 64, 2);
    gemm_mfma<<<ggrid, 256, 0, stream>>>(fb_hi, fb_lo,
                                         wbs_hi, wbs_lo, b1s, hs1h,
                                         wbd_hi, wbd_lo, b1d, hd1);

    // ---- CSR build ----
    const int eb = (NE + 255) / 256;
    count_deg<<<eb, 256, 0, stream>>>(dst, deg);
    deg_blocksum<<<NB, 256, 0, stream>>>(deg, bsum);
    scan_bsum<<<1, 256, 0, stream>>>(bsum);
    write_rows<<<NB, 256, 0, stream>>>(deg, bsum, row_start, cursor);
    scatter_src<<<eb, 256, 0, stream>>>(src, dst, cursor, src_sorted);

    gat1_fused<<<NN / 4, 256, 0, stream>>>(hs1h, hd1, attn1, src_sorted, row_start,
                                           W2s, b2s, W2d, b2d, hs2, hd2);

    node2_kernel<<<(NN + 15) / 16, 256, 0, stream>>>(hs2, hd2, attn2, src_sorted,
                                                     row_start, out);
}